// Round 8
// baseline (273.135 us; speedup 1.0000x reference)
//
#include <hip/hip_runtime.h>
#include <hip/hip_bf16.h>

typedef __bf16 bf16;
typedef __attribute__((ext_vector_type(4))) __bf16 bf16x4;
typedef __attribute__((ext_vector_type(8))) __bf16 bf16x8;
typedef __attribute__((ext_vector_type(4))) float f32x4;

#define MFMA16(a, b, c) __builtin_amdgcn_mfma_f32_16x16x32_bf16((a), (b), (c), 0, 0, 0)

// B=2, S=2048, D=512, H=8, hd=64, G=4. All I/O float32; bf16 MFMA compute.
static constexpr float EPS = 1e-5f;
static constexpr float LAMBDA_INIT = 0.2f;
static constexpr float LOG2E = 1.44269504088896340736f;

// Load 8 consecutive f32 (32B, 16B-aligned) and convert to bf16x8.
__device__ __forceinline__ bf16x8 cvt8(const float* p) {
    const f32x4 a = *(const f32x4*)p;
    const f32x4 b = *(const f32x4*)(p + 4);
    bf16x8 r;
    r[0] = (bf16)a[0]; r[1] = (bf16)a[1]; r[2] = (bf16)a[2]; r[3] = (bf16)a[3];
    r[4] = (bf16)b[0]; r[5] = (bf16)b[1]; r[6] = (bf16)b[2]; r[7] = (bf16)b[3];
    return r;
}

// Async 16B global -> LDS (lane i lands at lds_base + i*16; base wave-uniform).
__device__ __forceinline__ void gload_lds16(const void* g, void* l) {
    __builtin_amdgcn_global_load_lds(
        (const __attribute__((address_space(1))) unsigned int*)g,
        (__attribute__((address_space(3))) unsigned int*)l,
        16, 0, 0);
}

// ---------------------------------------------------------------------------
// Kernel 1: combined cvt + prep. [unchanged]
// ---------------------------------------------------------------------------
__global__ __launch_bounds__(256) void prep_kernel(
    const float* __restrict__ x,
    const float* __restrict__ q1w, const float* __restrict__ k1w,
    const float* __restrict__ q2w, const float* __restrict__ k2w,
    const float* __restrict__ vw,
    const float* __restrict__ ow, const float* __restrict__ gnw,
    const float* __restrict__ gnb,
    bf16* __restrict__ xb, bf16* __restrict__ wb,
    bf16* __restrict__ owg, float* __restrict__ S0, float* __restrict__ stats)
{
    const int tid = threadIdx.x;
    if (blockIdx.x < 1664) {
        const size_t base = ((size_t)blockIdx.x * 256 + tid) * 8;
        if (base < 2097152) {                    // x: 2*2048*512
            *(bf16x8*)(xb + base) = cvt8(x + base);
        } else {
            const size_t wbase = base - 2097152; // 0..1310720 (5 x 262144)
            const int wsel = (int)(wbase >> 18);
            const size_t off = wbase & 262143;
            const float* W = (wsel == 0) ? q1w : (wsel == 1) ? k1w :
                             (wsel == 2) ? q2w : (wsel == 3) ? k2w : vw;
            *(bf16x8*)(wb + wbase) = cvt8(W + off);
        }
        return;
    }

    __shared__ float red[4];
    const int pb = blockIdx.x - 1664;            // 0..31
    if (pb == 0 && tid < 16) stats[tid] = 0.f;

    const int n0 = pb * 16;
    const int c0 = tid, c1 = tid + 256;
    const float gw0 = gnw[c0], gw1 = gnw[c1];
    const float gb0 = gnb[c0], gb1 = gnb[c1];

    for (int n = 0; n < 16; ++n) {
        const size_t rowb = (size_t)(n0 + n) * 512;
        const float w0 = ow[rowb + c0];
        const float w1 = ow[rowb + c1];
        owg[rowb + c0] = (bf16)(w0 * gw0);
        owg[rowb + c1] = (bf16)(w1 * gw1);
        float s = gb0 * w0 + gb1 * w1;
#pragma unroll
        for (int off = 1; off < 64; off <<= 1) s += __shfl_xor(s, off, 64);
        if ((tid & 63) == 0) red[tid >> 6] = s;
        __syncthreads();
        if (tid == 0) S0[n0 + n] = red[0] + red[1] + red[2] + red[3];
        __syncthreads();
    }
}

// ---------------------------------------------------------------------------
// Kernel 2: fused QKV projection GEMM.
// This round: bijective XCD swizzle (640 = 8 x 80). The 20 blocks sharing an
// A-panel (and the 4 mb-groups sharing B-panels) now cluster on one XCD:
// per-XCD working set = 4 A-panels + 20 B-panels = 3.1 MB, L2-resident.
// K-loop and epilogues unchanged.
// ---------------------------------------------------------------------------
__global__ __launch_bounds__(256) void proj_kernel(
    const bf16* __restrict__ xb, const bf16* __restrict__ wb,
    const float* __restrict__ k1b, const float* __restrict__ k2b,
    bf16* __restrict__ q1o, bf16* __restrict__ k1o,
    bf16* __restrict__ q2o, bf16* __restrict__ k2o,
    bf16* __restrict__ vto)
{
    __shared__ __align__(16) bf16 sh[32768];   // 64 KB: As[2]|Bs[2]; reused as T
    bf16* const As0 = sh;
    bf16* const As1 = sh + 8192;
    bf16* const Bs0 = sh + 16384;
    bf16* const Bs1 = sh + 24576;

    const int tid = threadIdx.x;
    const int wave = tid >> 6, lane = tid & 63;
    const int l15 = lane & 15, quad = lane >> 4;
    const int wm = wave >> 1, wn = wave & 1;

    // XCD swizzle: 640 blocks = 8 XCDs x 80.
    const int swzb = (blockIdx.x & 7) * 80 + (blockIdx.x >> 3);
    const int mb = swzb / 20;
    const int nb = swzb % 20;
    const int wsel = nb >> 2;
    const int nrow0 = (nb & 3) * 128;

    const int srow = lane >> 3;                   // 0..7 row within chunk
    const int scol = 8 * ((lane & 7) ^ srow);     // swizzled source col
    const bf16* ag = xb + (size_t)(mb * 128 + srow) * 512 + scol;
    const bf16* bg = wb + (size_t)(wsel * 512 + nrow0 + srow) * 512 + scol;

    f32x4 acc[4][4];
#pragma unroll
    for (int i = 0; i < 4; ++i)
#pragma unroll
        for (int j = 0; j < 4; ++j)
            acc[i][j] = (f32x4){0.f, 0.f, 0.f, 0.f};

#define STAGE_PROJ(abuf, bbuf, s) do {                                         \
    const int k0_ = (s) * 64;                                                  \
    _Pragma("unroll")                                                          \
    for (int c_ = 0; c_ < 4; ++c_) {                                           \
        const int chunk_ = wave * 4 + c_;                                      \
        gload_lds16(ag + (size_t)(chunk_ * 8) * 512 + k0_, (abuf) + chunk_ * 512); \
        gload_lds16(bg + (size_t)(chunk_ * 8) * 512 + k0_, (bbuf) + chunk_ * 512); \
    }                                                                          \
} while (0)

    STAGE_PROJ(As0, Bs0, 0);
    __syncthreads();

    const int ka = 8 * (quad ^ (l15 & 7));        // k 0..31 chunk (swizzled)

    for (int s = 0; s < 8; ++s) {
        const bf16* Ac = (s & 1) ? As1 : As0;
        const bf16* Bc = (s & 1) ? Bs1 : Bs0;
        if (s < 7) {
            if (s & 1) STAGE_PROJ(As0, Bs0, s + 1);
            else       STAGE_PROJ(As1, Bs1, s + 1);
        }

        bf16x8 al[4], ah[4], bl[4], bh_[4];
#pragma unroll
        for (int i = 0; i < 4; ++i) {
            const bf16* p = Ac + (wm * 64 + i * 16 + l15) * 64;
            al[i] = *(const bf16x8*)(p + ka);
            ah[i] = *(const bf16x8*)(p + (ka ^ 32));
        }
#pragma unroll
        for (int j = 0; j < 4; ++j) {
            const bf16* p = Bc + (wn * 64 + j * 16 + l15) * 64;
            bl[j]  = *(const bf16x8*)(p + ka);
            bh_[j] = *(const bf16x8*)(p + (ka ^ 32));
        }

#pragma unroll
        for (int i = 0; i < 4; ++i)
#pragma unroll
            for (int j = 0; j < 4; ++j) {
                acc[i][j] = MFMA16(al[i], bl[j], acc[i][j]);
                acc[i][j] = MFMA16(ah[i], bh_[j], acc[i][j]);
            }

        __syncthreads();
    }

    const int bidx = mb >> 4;
    const int sbase = (mb & 15) * 128;
    const float scale = (wsel == 0 || wsel == 2) ? 0.125f * LOG2E : 1.0f;

    if (wsel != 4) {
        // ---- q/k epilogue: T[m][n ^ (quad(m)<<4)], then linear head chunks.
        bf16* const T = sh;                       // 128x128 bf16 = 32 KB
        const int swzq = quad << 4;               // (m>>2)&3 == quad here
#pragma unroll
        for (int j = 0; j < 4; ++j) {
            const int nl = wn * 64 + j * 16 + l15;
            const int ncol = nrow0 + nl;
            float bias = 0.f;
            if (wsel == 1) bias = k1b[ncol];
            if (wsel == 3) bias = k2b[ncol];
            const int nswz = nl ^ swzq;
#pragma unroll
            for (int i = 0; i < 4; ++i) {
                const int mbase = wm * 64 + i * 16 + quad * 4;
#pragma unroll
                for (int r = 0; r < 4; ++r)
                    T[(mbase + r) * 128 + nswz] = (bf16)(acc[i][j][r] * scale + bias);
            }
        }
        __syncthreads();

        bf16* const dst = (wsel == 0) ? q1o : (wsel == 1) ? k1o :
                          (wsel == 2) ? q2o : k2o;
#pragma unroll
        for (int hsel = 0; hsel < 2; ++hsel) {
            const int h = (nrow0 >> 6) + hsel;
            bf16* db = dst + ((size_t)(bidx * 8 + h) * 2048 + sbase) * 64;
#pragma unroll
            for (int ps = 0; ps < 4; ++ps) {
                const int idx = (ps * 256 + tid) * 8;     // 0..8191
                const int m = idx >> 6, hd = idx & 63;
                const bf16x8 v = *(const bf16x8*)(
                    T + m * 128 + ((hsel * 64 + hd) ^ (((m >> 2) & 3) << 4)));
                *(bf16x8*)(db + idx) = v;
            }
        }
    } else {
        // ---- V epilogue: Tt[n][sp] (pitch 132, 4-elem XOR swizzle), with the
        // period-32 s-permutation folded into the column index; then 256B rows.
        bf16* const Tt = sh;                      // 128x132 bf16 = 33 KB
#pragma unroll
        for (int j = 0; j < 4; ++j) {
            const int nl = wn * 64 + j * 16 + l15;
            const int hd = (nrow0 + nl) & 63;
            const int xh = (hd >> 1) & 3;
            const int swz = (nl & 7) << 2;
#pragma unroll
            for (int i = 0; i < 4; ++i) {
                const int colb = (wm * 64 + (i >> 1) * 32 + ((quad ^ xh) << 3)
                                  + ((i & 1) << 2)) ^ swz;
                bf16x4 pk;
#pragma unroll
                for (int r = 0; r < 4; ++r) pk[r] = (bf16)acc[i][j][r];
                *(bf16x4*)(Tt + nl * 132 + colb) = pk;
            }
        }
        __syncthreads();

#pragma unroll
        for (int ps = 0; ps < 8; ++ps) {
            const int rown = ps * 16 + (tid >> 4);        // n_local 0..127
            const int seg = tid & 15;                     // 8-elem segment
            const int swz = (rown & 7) << 2;
            const bf16x4 lo = *(const bf16x4*)(Tt + rown * 132 + ((seg * 8) ^ swz));
            const bf16x4 hi = *(const bf16x4*)(Tt + rown * 132 + ((seg * 8 + 4) ^ swz));
            const int ncol = nrow0 + rown;
            const int h = ncol >> 6, hd = ncol & 63;
            bf16x8 v;
            v[0] = lo[0]; v[1] = lo[1]; v[2] = lo[2]; v[3] = lo[3];
            v[4] = hi[0]; v[5] = hi[1]; v[6] = hi[2]; v[7] = hi[3];
            *(bf16x8*)(vto + ((size_t)(bidx * 8 + h) * 64 + hd) * 2048
                       + sbase + seg * 8) = v;
        }
    }
#undef STAGE_PROJ
}

// ---------------------------------------------------------------------------
// Kernel 3: dual-stream flash attention + fused GroupNorm partial stats.
// This round: K DIRECT-TO-REGISTER (no LDS round trip for K). In the r7
// (qp,st,kg) decomposition each wave needs only 4 K fragments/iter, and the
// swizzled-LDS path provably returns the linear global fragment — so load K
// straight from global (L2-resident). Halves LDS reads again (only V), cuts
// staging to 1 gload/wave, drops K address swizzle math. K double-buffers in
// NAMED regs (kcA/kcB, manual 2-unroll per rule #20). LDS now 32 KB.
// ---------------------------------------------------------------------------
__global__ __launch_bounds__(512, 4) void attn_kernel(
    const bf16* __restrict__ q1, const bf16* __restrict__ k1,
    const bf16* __restrict__ q2, const bf16* __restrict__ k2,
    const bf16* __restrict__ vt,
    const float* __restrict__ lq1, const float* __restrict__ lk1,
    const float* __restrict__ lq2, const float* __restrict__ lk2,
    bf16* __restrict__ o, float* __restrict__ stats)
{
    __shared__ __align__(16) bf16 smem[16384];   // 32 KB: vb0|vb1 (16KB) / reduction (32KB)
    __shared__ float lbuf[8][2][16];
    __shared__ float sred[2][2];

    bf16* const vb0 = smem;          // 4096 elems = 8 KB
    bf16* const vb1 = smem + 4096;

    const int tid = threadIdx.x;
    const int wave = tid >> 6;
    const int lane = tid & 63;
    const int l15 = lane & 15, quad = lane >> 4;
    const int kg = wave >> 2;         // key group (0: keys 0..1023, 1: 1024..)
    const int w4 = wave & 3;
    const int qp = w4 & 1;            // q-pair: tiles {2qp, 2qp+1}
    const int st = w4 >> 1;           // stream: 0 -> (q1,k1), 1 -> (q2,k2)

    // XCD-aware remap (512 = 8 XCDs x 64, bijective).
    const int rid = (blockIdx.x & 7) * 64 + (blockIdx.x >> 3);
    const int bh = rid >> 5;
    const int qt = rid & 31;
    const int b = bh >> 3, h = bh & 7;

    const bf16* kst = (st ? k2 : k1) + (size_t)bh * 2048 * 64;
    const bf16* vtt = vt + (size_t)bh * 64 * 2048;

    // Q fragments for this wave's stream, 2 q-tiles (rows qp*32 .. qp*32+31).
    const bf16* qs = st ? q2 : q1;
    const int qrowA = qt * 64 + qp * 32 + l15;
    const bf16* qpA = qs + ((size_t)bh * 2048 + qrowA) * 64 + quad * 8;
    const bf16x8 qA0 = *(const bf16x8*)(qpA);
    const bf16x8 qA1 = *(const bf16x8*)(qpA + 32);
    const bf16x8 qB0 = *(const bf16x8*)(qpA + 16 * 64);
    const bf16x8 qB1 = *(const bf16x8*)(qpA + 16 * 64 + 32);

    // Per-lane K base: fragment f(row_off, hd_off) at kpl + it*2048 +
    // {0, 32, 1024, 1056}  (row_off in {0,16} keys, hd_off in {0,32}).
    const bf16* kpl = kst + (size_t)(kg * 1024 + l15) * 64 + quad * 8;

    // V staging (unchanged pattern; dest buffers now V-only).
    const int sw = wave & 3;
    const int skey0 = (wave < 4) ? 0 : 1024;
    const size_t vsrc0 = (size_t)(sw * 16 + (lane >> 2)) * 2048 + skey0 + (lane & 3) * 8;

#define STAGE_V(buf, itv) \
    gload_lds16(vtt + vsrc0 + (itv) * 32, (buf) + wave * 512)

    const int vsw = 8 * (quad ^ ((l15 >> 1) & 3));   // matches proj's xh perm

    f32x4 OA[4], OB[4];
    float lA = 0.f, lB = 0.f;
#pragma unroll
    for (int t = 0; t < 4; ++t) {
        OA[t] = (f32x4){0.f, 0.f, 0.f, 0.f};
        OB[t] = (f32x4){0.f, 0.f, 0.f, 0.f};
    }

    // Named K double-buffer registers (no arrays -> no scratch).
    bf16x8 kA0, kA1, kA2, kA3, kB0, kB1, kB2, kB3;

    // Prologue: K(0) -> kcA, V(0) -> vb0.
    kA0 = *(const bf16x8*)(kpl);
    kA1 = *(const bf16x8*)(kpl + 32);
    kA2 = *(const bf16x8*)(kpl + 1024);
    kA3 = *(const bf16x8*)(kpl + 1056);
    STAGE_V(vb0, 0);
    __syncthreads();

#define ATTN_BODY(KF0, KF1, KF2, KF3, VB)                                     \
    do {                                                                      \
        const bf16* vr = (VB) + kg * 2048;                                    \
        const bf16x8 v0 = *(const bf16x8*)(vr + l15 * 32 + vsw);              \
        const bf16x8 v1 = *(const bf16x8*)(vr + (16 + l15) * 32 + vsw);       \
        const bf16x8 v2 = *(const bf16x8*)(vr + (32 + l15) * 32 + vsw);       \
        const bf16x8 v3 = *(const bf16x8*)(vr + (48 + l15) * 32 + vsw);       \
        const f32x4 z = (f32x4){0.f, 0.f, 0.f, 0.f};                          \
        __builtin_amdgcn_s_setprio(1);                                        \
        f32x4 sA0 = MFMA16(KF0, qA0, z);  sA0 = MFMA16(KF1, qA1, sA0);        \
        f32x4 sA1 = MFMA16(KF2, qA0, z);  sA1 = MFMA16(KF3, qA1, sA1);        \
        f32x4 sB0 = MFMA16(KF0, qB0, z);  sB0 = MFMA16(KF1, qB1, sB0);        \
        f32x4 sB1 = MFMA16(KF2, qB0, z);  sB1 = MFMA16(KF3, qB1, sB1);        \
        __builtin_amdgcn_s_setprio(0);                                        \
        bf16x8 bA, bB;                                                        \
        _Pragma("unroll")                                                     \
        for (int r = 0; r < 4; ++r) {                                         \
            float e;                                                          \
            e = __builtin_amdgcn_exp2f(sA0[r]); lA += e; bA[r]     = (bf16)e; \
            e = __builtin_amdgcn_exp2f(sA1[r]); lA += e; bA[4 + r] = (bf16)e; \
            e = __builtin_amdgcn_exp2f(sB0[r]); lB += e; bB[r]     = (bf16)e; \
            e = __builtin_amdgcn_exp2f(sB1[r]); lB += e; bB[4 + r] = (bf16)e; \
        }                                                                     \
        __builtin_amdgcn_s_setprio(1);                                        \
        OA[0] = MFMA16(v0, bA, OA[0]);                                        \
        OA[1] = MFMA16(v1, bA, OA[1]);                                        \
        OA[2] = MFMA16(v2, bA, OA[2]);                                        \
        OA[3] = MFMA16(v3, bA, OA[3]);                                        \
        OB[0] = MFMA16(v0, bB, OB[0]);                                        \
        OB[1] = MFMA16(v1, bB, OB[1]);                                        \
        OB[2] = MFMA16(v2, bB, OB[2]);                                        \
        OB[3] = MFMA16(v3, bB, OB[3]);                                        \
        __builtin_amdgcn_s_setprio(0);                                        \
    } while (0)

    for (int it2 = 0; it2 < 16; ++it2) {
        const int itE = it2 * 2;
        // EVEN iter: compute kcA/vb0; prefetch K(itE+1)->kcB, V(itE+1)->vb1.
        {
            const bf16* kn = kpl + (size_t)(itE + 1) * 2048;
            kB0 = *(const bf16x8*)(kn);
            kB1 = *(const bf16x8*)(kn + 32);
            kB2 = *(const bf16x8*)(kn + 1024);
            kB3 = *(const bf16x8*)(kn + 1056);
            STAGE_V(vb1, itE + 1);
        }
        ATTN_BODY(kA0, kA1, kA2, kA3, vb0);
        __syncthreads();

        // ODD iter: compute kcB/vb1; prefetch K(itE+2)->kcA, V(itE+2)->vb0.
        if (itE + 2 < 32) {
            const bf16* kn = kpl + (size_t)(itE + 2) * 2048;
            kA0 = *(const bf16x8*)(kn);
            kA1 = *(const bf16x8*)(kn + 32);
            kA2 = *(const bf16x8*)(kn + 1024);
            kA3 = *(const bf16x8*)(kn + 1056);
            STAGE_V(vb0, itE + 2);
        }
        ATTN_BODY(kB0, kB1, kB2, kB3, vb1);
        __syncthreads();
    }

    // Quad-replica reduce of l, publish per-wave partial l.
    lA += __shfl_xor(lA, 16, 64);  lA += __shfl_xor(lA, 32, 64);
    lB += __shfl_xor(lB, 16, 64);  lB += __shfl_xor(lB, 32, 64);
    if (lane < 16) {
        lbuf[wave][0][lane] = lA;
        lbuf[wave][1][lane] = lB;
    }
    __syncthreads();

    // Stage 1: kg-combine. kg=1 waves export OA,OB; kg=0 waves accumulate.
    f32x4* rb = (f32x4*)smem;                     // 2048 f32x4 = 32 KB
    if (kg == 1) {
        f32x4* dst = rb + w4 * 512;
#pragma unroll
        for (int t = 0; t < 4; ++t) {
            dst[t * 64 + lane]       = OA[t];
            dst[(4 + t) * 64 + lane] = OB[t];
        }
    }
    __syncthreads();
    if (kg == 0) {
        const f32x4* src = rb + w4 * 512;
#pragma unroll
        for (int t = 0; t < 4; ++t) {
            OA[t] += src[t * 64 + lane];
            OB[t] += src[(4 + t) * 64 + lane];
        }
    }
    __syncthreads();

    // Stage 2: stream-combine. kg=0,st=1 waves (2,3) export full-key O2.
    if (kg == 0 && st == 1) {
        f32x4* dst = rb + qp * 512;
#pragma unroll
        for (int t = 0; t < 4; ++t) {
            dst[t * 64 + lane]       = OA[t];
            dst[(4 + t) * 64 + lane] = OB[t];
        }
    }
    __syncthreads();

    float ssum = 0.f, ssq = 0.f;
    if (kg == 0 && st == 0) {                     // waves 0,1: final combine
        const f32x4* src = rb + qp * 512;         // stream-2 full-key O
        const float L1A = lA + lbuf[4 + qp][0][l15];
        const float L1B = lB + lbuf[4 + qp][1][l15];
        const float L2A = lbuf[2 + qp][0][l15] + lbuf[6 + qp][0][l15];
        const float L2B = lbuf[2 + qp][1][l15] + lbuf[6 + qp][1][l15];
        const float lam = __expf(lq1[h] * lk1[h]) - __expf(lq2[h] * lk2[h]) + LAMBDA_INIT;
        const float i1A = 1.f / L1A, i2A = lam / L2A;
        const float i1B = 1.f / L1B, i2B = lam / L2B;
        const size_t rowA = (size_t)(b * 2048 + qt * 64 + qp * 32 + l15) * 512 + h * 64;
        const size_t rowB = rowA + 16 * 512;
#pragma unroll
        for (int t = 0; t < 4; ++t) {
            const f32x4 o2A = src[t * 64 + lane];
            const f32x4 o2B = src[(4 + t) * 64 + lane];
#pragma unroll
            for (int r = 0; r < 4; ++r) {
                const float vA = OA[t][r] * i1A - o2A[r] * i2A;
                const float vB = OB[t][r] * i1B - o2B[r] * i2B;
                ssum += vA + vB;
                ssq += vA * vA + vB * vB;
                o[rowA + t * 16 + quad * 4 + r] = (bf16)vA;
                o[rowB + t * 16 + quad * 4 + r] = (bf16)vB;
            }
        }
    }
#pragma unroll
    for (int off = 1; off < 64; off <<= 1) {
        ssum += __shfl_xor(ssum, off, 64);
        ssq += __shfl_xor(ssq, off, 64);
    }
    if (kg == 0 && st == 0 && lane == 0) { sred[qp][0] = ssum; sred[qp][1] = ssq; }
    __syncthreads();
    if (tid == 0) {
        const float s0 = sred[0][0] + sred[1][0];
        const float s1 = sred[0][1] + sred[1][1];
        const int bg = b * 4 + (h >> 1);
        atomicAdd(&stats[bg * 2], s0);
        atomicAdd(&stats[bg * 2 + 1], s1);
    }
#undef STAGE_V
#undef ATTN_BODY
}

// ---------------------------------------------------------------------------
// Kernel 4: output GEMM with GN folded algebraically.
// This round: bijective XCD swizzle (512 = 8 x 64): per-XCD working set =
// 8 A-panels + whole owg = 1 MB, L2-resident. Loop/epilogue unchanged.
// ---------------------------------------------------------------------------
__global__ __launch_bounds__(256) void out_gemm_kernel(
    const bf16* __restrict__ o, const bf16* __restrict__ owg,
    const float* __restrict__ S0, const float* __restrict__ stats,
    const float* __restrict__ ob, float* __restrict__ y)
{
    __shared__ __align__(16) bf16 sh[24576];   // 48 KB: 3x(A|B); reused as Tf

    const int tid = threadIdx.x;
    const int wave = tid >> 6, lane = tid & 63;
    const int l15 = lane & 15, quad = lane >> 4;

    // XCD swizzle: 512 blocks = 8 XCDs x 64.
    const int swzb = (blockIdx.x & 7) * 64 + (blockIdx.x >> 3);
    const int mb = swzb >> 3;
    const int nb = swzb & 7;
    const int b = mb >> 5;

    const float N = 128.f * 2048.f;
    float mu[4], rs[4];
#pragma unroll
    for (int g = 0; g < 4; ++g) {
        const float m = stats[(b * 4 + g) * 2] / N;
        const float var = stats[(b * 4 + g) * 2 + 1] / N - m * m;
        mu[g] = m;
        rs[g] = rsqrtf(var + EPS);
    }

    const int srow = lane >> 3;                   // 0..7
    const int scol = 8 * ((lane & 7) ^ srow);     // swizzled source col
    const bf16* ag = o + (size_t)(mb * 64 + srow) * 512 + scol;
    const bf16* bg = owg + (size_t)(nb * 64 + srow) * 512 + scol;

#define STAGE_OUT(abuf, bbuf, s) do {                                          \
    const int k0_ = (s) * 64;                                                  \
    _Pragma("unroll")                                                          \
    for (int c_ = 0; c_ < 2; ++c_) {                                           \
        const int chunk_ = wave * 2 + c_;                                      \
        gload_lds16(ag + (size_t)(chunk_ * 8) * 512 + k0_, (abuf) + chunk_ * 512); \
        gload_lds16(bg + (size_t)(chunk_ * 8) * 512 + k0_, (bbuf) + chunk_ * 512); \
    }                                                                          \
} while (0)

    f32x4 acc[4], tot[4];
#pragma unroll
    for (int i = 0; i < 4; ++i) {
        acc[i] = (f32x4){0.f, 0.f, 0.f, 0.f};
        tot[i] = (f32x4){0.f, 0.f, 0.f, 0.f};
    }
    float s1g[4];
    float s1p = 0.f;
#pragma unroll
    for (int g = 0; g < 4; ++g) s1g[g] = 0.f;

    // Prologue: stage kk=0 and kk=1 (8 loads in flight per wave).
    STAGE_OUT(sh, sh + 12288, 0);
    STAGE_OUT(sh + 4096, sh + 12288 + 4096, 1);

    const int ka = 8 * (quad ^ (l15 & 7));

    int cur = 0;
    for (int kk = 0; kk < 8; ++kk) {
        if (kk < 7) {
            asm volatile("s_waitcnt vmcnt(4) lgkmcnt(0)\ns_barrier" ::: "memory");
        } else {
            asm volatile("s_waitcnt vmcnt(0) lgkmcnt(0)\ns_barrier" ::: "memory");
        }
        __builtin_amdgcn_sched_barrier(0);

        const bf16* Ac = sh + cur * 4096;
        const bf16* Bc = sh + 12288 + cur * 4096;
        const int n2 = (cur == 0) ? 2 : cur - 1;      // (cur+2)%3
        if (kk < 6) STAGE_OUT(sh + n2 * 4096, sh + 12288 + n2 * 4096, kk + 2);

        bf16x8 al[4], ah[4];
#pragma unroll
        for (int i = 0; i < 4; ++i) {
            const bf16* p = Ac + (i * 16 + l15) * 64;
            al[i] = *(const bf16x8*)(p + ka);
            ah[i] = *(const bf16x8*)(p + (ka ^ 32));
        }
        const bf16* pb = Bc + (wave * 16 + l15) * 64;
        const bf16x8 bl = *(const bf16x8*)(pb + ka);
        const bf16x8 bh = *(const bf16x8*)(pb + (ka ^ 32));

#pragma unroll
        for (int i = 0; i < 4; ++i) {
            acc[i] = MFMA16(al[i], bl, acc[i]);
            acc[i] = MFMA16(ah[i], bh, acc[i]);
        }

#pragma unroll
        for (int j = 0; j < 8; ++j) s1p += (float)bl[j] + (float)bh[j];

        if (kk & 1) {
            const int g = kk >> 1;
#pragma unroll
            for (int i = 0; i < 4; ++i) {
#pragma unroll
                for (int r = 0; r < 4; ++r) tot[i][r] += rs[g] * acc[i][r];
                acc[i] = (f32x4){0.f, 0.f, 0.f, 0.f};
            }
            float sg = s1p + __shfl_xor(s1p, 16, 64);
            sg += __shfl_xor(sg, 32, 64);
            s1g[g] = sg;
            s1p = 0.f;
        }

        cur = (cur == 2) ? 0 : cur + 1;
    }
    __syncthreads();      // all waves past the loop; sh reusable as Tf

    const int ncol = nb * 64 + wave * 16 + l15;
    float bias = S0[ncol] + ob[ncol];
#pragma unroll
    for (int g = 0; g < 4; ++g) bias -= mu[g] * rs[g] * s1g[g];

    // LDS-staged epilogue: Tf[m][n ^ (quad(m)<<4)] f32, then coalesced rows.
    float* const Tf = (float*)sh;                 // 64x64 f32 = 16 KB
    const int nl = wave * 16 + l15;
#pragma unroll
    for (int i = 0; i < 4; ++i) {
        const int mbase = i * 16 + quad * 4;
#pragma unroll
        for (int r = 0; r < 4; ++r)
            Tf[(mbase + r) * 64 + (nl ^ (quad << 4))] = tot[i][r] + bias;
    }
    __syncthreads();

#pragma unroll
    for (int ps = 0; ps < 4; ++ps) {
        const int idx = (ps * 256 + tid) * 4;     // 0..4095
        const int m = idx >> 6, n4 = idx & 63;
        const f32x4 v = *(const f32x4*)(Tf + m * 64 + (n4 ^ (((m >> 2) & 3) << 4)));
        *(f32x4*)(y + (size_t)(mb * 64 + m) * 512 + nb * 64 + n4) = v;
    }
#undef STAGE_OUT
}

// ---------------------------------------------------------------------------
extern "C" void kernel_launch(void* const* d_in, const int* in_sizes, int n_in,
                              void* d_out, int out_size, void* d_ws, size_t ws_size,
                              hipStream_t stream)
{
    const float* x   = (const float*)d_in[0];
    const float* K1w = (const float*)d_in[1];
    const float* K1b = (const float*)d_in[2];
    const float* Q1w = (const float*)d_in[3];
    const float* K2w = (const float*)d_in[4];
    const float* K2b = (const float*)d_in[5];
    const float* Q2w = (const float*)d_in[6];
    const float* Vw  = (const float*)d_in[7];
    const float* lq1 = (const float*)d_in[8];
    const float* lk1 = (const float*)d_in[9];
    const float* lq2 = (const float*)d_in[10];
    const float* lk2 = (const float*)d_in[11];
    const float* gnw = (const float*)d_in[12];
    const float* gnb = (const float*)d_in[13];
    const float* Ow  = (const float*)d_in[14];
    const float* Ob  = (const float*)d_in[15];

    const size_t SZ = (size_t)2 * 8 * 2048 * 64;   // 2M elements per tensor
    bf16* q1 = (bf16*)d_ws;
    bf16* k1 = q1 + SZ;
    bf16* q2 = k1 + SZ;
    bf16* k2 = q2 + SZ;
    bf16* vt = k2 + SZ;
    bf16* o  = vt + SZ;                 // attn output; slot shared with xb
    bf16* xb = o;                       // x bf16 (2M elems) — dead before attn writes o
    bf16* wb = o + SZ;                  // 2560x512 bf16 (2.6 MB)
    bf16* owg = wb + (size_t)2560 * 512;
    float* S0 = (float*)(owg + 512 * 512);
    float* stats = S0 + 512;

    prep_kernel<<<1696, 256, 0, stream>>>(x, Q1w, K1w, Q2w, K2w, Vw,
                                          Ow, gnw, gnb, xb, wb, owg, S0, stats);
    proj_kernel<<<640, 256, 0, stream>>>(xb, wb, K1b, K2b,
                                         q1, k1, q2, k2, vt);
    attn_kernel<<<512, 512, 0, stream>>>(q1, k1, q2, k2, vt,
                                         lq1, lk1, lq2, lk2, o, stats);
    out_gemm_kernel<<<512, 256, 0, stream>>>(o, owg, S0, stats, Ob,
                                             (float*)d_out);
}

// Round 9
// 180.723 us; speedup vs baseline: 1.5113x; 1.5113x over previous
//
#include <hip/hip_runtime.h>
#include <hip/hip_bf16.h>

typedef __bf16 bf16;
typedef __attribute__((ext_vector_type(4))) __bf16 bf16x4;
typedef __attribute__((ext_vector_type(8))) __bf16 bf16x8;
typedef __attribute__((ext_vector_type(4))) float f32x4;

#define MFMA16(a, b, c) __builtin_amdgcn_mfma_f32_16x16x32_bf16((a), (b), (c), 0, 0, 0)

// B=2, S=2048, D=512, H=8, hd=64, G=4. All I/O float32; bf16 MFMA compute.
static constexpr float EPS = 1e-5f;
static constexpr float LAMBDA_INIT = 0.2f;
static constexpr float LOG2E = 1.44269504088896340736f;

// Load 8 consecutive f32 (32B, 16B-aligned) and convert to bf16x8.
__device__ __forceinline__ bf16x8 cvt8(const float* p) {
    const f32x4 a = *(const f32x4*)p;
    const f32x4 b = *(const f32x4*)(p + 4);
    bf16x8 r;
    r[0] = (bf16)a[0]; r[1] = (bf16)a[1]; r[2] = (bf16)a[2]; r[3] = (bf16)a[3];
    r[4] = (bf16)b[0]; r[5] = (bf16)b[1]; r[6] = (bf16)b[2]; r[7] = (bf16)b[3];
    return r;
}

// Async 16B global -> LDS (lane i lands at lds_base + i*16; base wave-uniform).
__device__ __forceinline__ void gload_lds16(const void* g, void* l) {
    __builtin_amdgcn_global_load_lds(
        (const __attribute__((address_space(1))) unsigned int*)g,
        (__attribute__((address_space(3))) unsigned int*)l,
        16, 0, 0);
}

// ---------------------------------------------------------------------------
// Kernel 1 (was 2): fused QKV projection GEMM, now reading x / weights
// DIRECTLY from f32 (cvt8 during reg-staging; ds_write_b128 to the same
// linear LDS layout gload_lds produced, so compute side is unchanged).
// prep_kernel is DELETED — this kernel also zeroes stats. XCD swizzle kept.
// ---------------------------------------------------------------------------
__global__ __launch_bounds__(256) void proj_kernel(
    const float* __restrict__ x,
    const float* __restrict__ q1w, const float* __restrict__ k1w,
    const float* __restrict__ q2w, const float* __restrict__ k2w,
    const float* __restrict__ vw,
    const float* __restrict__ k1b, const float* __restrict__ k2b,
    bf16* __restrict__ q1o, bf16* __restrict__ k1o,
    bf16* __restrict__ q2o, bf16* __restrict__ k2o,
    bf16* __restrict__ vto, float* __restrict__ stats)
{
    __shared__ __align__(16) bf16 sh[32768];   // 64 KB: As[2]|Bs[2]; reused as T
    bf16* const As0 = sh;
    bf16* const As1 = sh + 8192;
    bf16* const Bs0 = sh + 16384;
    bf16* const Bs1 = sh + 24576;

    const int tid = threadIdx.x;
    if (blockIdx.x == 0 && tid < 16) stats[tid] = 0.f;   // attn runs after us

    const int wave = tid >> 6, lane = tid & 63;
    const int l15 = lane & 15, quad = lane >> 4;
    const int wm = wave >> 1, wn = wave & 1;

    // XCD swizzle: 640 blocks = 8 XCDs x 80.
    const int swzb = (blockIdx.x & 7) * 80 + (blockIdx.x >> 3);
    const int mb = swzb / 20;
    const int nb = swzb % 20;
    const int wsel = nb >> 2;
    const int nrow0 = (nb & 3) * 128;

    const float* W = (wsel == 0) ? q1w : (wsel == 1) ? k1w :
                     (wsel == 2) ? q2w : (wsel == 3) ? k2w : vw;

    const int srow = lane >> 3;                   // 0..7 row within chunk
    const int scol = 8 * ((lane & 7) ^ srow);     // swizzled source col
    const float* ag = x + (size_t)(mb * 128 + srow) * 512 + scol;
    const float* bg = W + (size_t)(nrow0 + srow) * 512 + scol;

    f32x4 acc[4][4];
#pragma unroll
    for (int i = 0; i < 4; ++i)
#pragma unroll
        for (int j = 0; j < 4; ++j)
            acc[i][j] = (f32x4){0.f, 0.f, 0.f, 0.f};

    // Reg-stage f32 -> cvt -> ds_write. Dest (chunk*512 + lane*8) matches the
    // old gload_lds lane placement exactly, so the LDS image is identical.
#define STAGE_PROJ(abuf, bbuf, s) do {                                         \
    const int k0_ = (s) * 64;                                                  \
    _Pragma("unroll")                                                          \
    for (int c_ = 0; c_ < 4; ++c_) {                                           \
        const int chunk_ = wave * 4 + c_;                                      \
        *(bf16x8*)((abuf) + chunk_ * 512 + lane * 8) =                         \
            cvt8(ag + (size_t)(chunk_ * 8) * 512 + k0_);                       \
        *(bf16x8*)((bbuf) + chunk_ * 512 + lane * 8) =                         \
            cvt8(bg + (size_t)(chunk_ * 8) * 512 + k0_);                       \
    }                                                                          \
} while (0)

    STAGE_PROJ(As0, Bs0, 0);
    __syncthreads();

    const int ka = 8 * (quad ^ (l15 & 7));        // k 0..31 chunk (swizzled)

    for (int s = 0; s < 8; ++s) {
        const bf16* Ac = (s & 1) ? As1 : As0;
        const bf16* Bc = (s & 1) ? Bs1 : Bs0;
        if (s < 7) {
            if (s & 1) STAGE_PROJ(As0, Bs0, s + 1);
            else       STAGE_PROJ(As1, Bs1, s + 1);
        }

        bf16x8 al[4], ah[4], bl[4], bh_[4];
#pragma unroll
        for (int i = 0; i < 4; ++i) {
            const bf16* p = Ac + (wm * 64 + i * 16 + l15) * 64;
            al[i] = *(const bf16x8*)(p + ka);
            ah[i] = *(const bf16x8*)(p + (ka ^ 32));
        }
#pragma unroll
        for (int j = 0; j < 4; ++j) {
            const bf16* p = Bc + (wn * 64 + j * 16 + l15) * 64;
            bl[j]  = *(const bf16x8*)(p + ka);
            bh_[j] = *(const bf16x8*)(p + (ka ^ 32));
        }

#pragma unroll
        for (int i = 0; i < 4; ++i)
#pragma unroll
            for (int j = 0; j < 4; ++j) {
                acc[i][j] = MFMA16(al[i], bl[j], acc[i][j]);
                acc[i][j] = MFMA16(ah[i], bh_[j], acc[i][j]);
            }

        __syncthreads();
    }

    const int bidx = mb >> 4;
    const int sbase = (mb & 15) * 128;
    const float scale = (wsel == 0 || wsel == 2) ? 0.125f * LOG2E : 1.0f;

    if (wsel != 4) {
        // ---- q/k epilogue: T[m][n ^ (quad(m)<<4)], then linear head chunks.
        bf16* const T = sh;                       // 128x128 bf16 = 32 KB
        const int swzq = quad << 4;               // (m>>2)&3 == quad here
#pragma unroll
        for (int j = 0; j < 4; ++j) {
            const int nl = wn * 64 + j * 16 + l15;
            const int ncol = nrow0 + nl;
            float bias = 0.f;
            if (wsel == 1) bias = k1b[ncol];
            if (wsel == 3) bias = k2b[ncol];
            const int nswz = nl ^ swzq;
#pragma unroll
            for (int i = 0; i < 4; ++i) {
                const int mbase = wm * 64 + i * 16 + quad * 4;
#pragma unroll
                for (int r = 0; r < 4; ++r)
                    T[(mbase + r) * 128 + nswz] = (bf16)(acc[i][j][r] * scale + bias);
            }
        }
        __syncthreads();

        bf16* const dst = (wsel == 0) ? q1o : (wsel == 1) ? k1o :
                          (wsel == 2) ? q2o : k2o;
#pragma unroll
        for (int hsel = 0; hsel < 2; ++hsel) {
            const int h = (nrow0 >> 6) + hsel;
            bf16* db = dst + ((size_t)(bidx * 8 + h) * 2048 + sbase) * 64;
#pragma unroll
            for (int ps = 0; ps < 4; ++ps) {
                const int idx = (ps * 256 + tid) * 8;     // 0..8191
                const int m = idx >> 6, hd = idx & 63;
                const bf16x8 v = *(const bf16x8*)(
                    T + m * 128 + ((hsel * 64 + hd) ^ (((m >> 2) & 3) << 4)));
                *(bf16x8*)(db + idx) = v;
            }
        }
    } else {
        // ---- V epilogue: Tt[n][sp] (pitch 132, 4-elem XOR swizzle), with the
        // period-32 s-permutation folded into the column index; then 256B rows.
        bf16* const Tt = sh;                      // 128x132 bf16 = 33 KB
#pragma unroll
        for (int j = 0; j < 4; ++j) {
            const int nl = wn * 64 + j * 16 + l15;
            const int hd = (nrow0 + nl) & 63;
            const int xh = (hd >> 1) & 3;
            const int swz = (nl & 7) << 2;
#pragma unroll
            for (int i = 0; i < 4; ++i) {
                const int colb = (wm * 64 + (i >> 1) * 32 + ((quad ^ xh) << 3)
                                  + ((i & 1) << 2)) ^ swz;
                bf16x4 pk;
#pragma unroll
                for (int r = 0; r < 4; ++r) pk[r] = (bf16)acc[i][j][r];
                *(bf16x4*)(Tt + nl * 132 + colb) = pk;
            }
        }
        __syncthreads();

#pragma unroll
        for (int ps = 0; ps < 8; ++ps) {
            const int rown = ps * 16 + (tid >> 4);        // n_local 0..127
            const int seg = tid & 15;                     // 8-elem segment
            const int swz = (rown & 7) << 2;
            const bf16x4 lo = *(const bf16x4*)(Tt + rown * 132 + ((seg * 8) ^ swz));
            const bf16x4 hi = *(const bf16x4*)(Tt + rown * 132 + ((seg * 8 + 4) ^ swz));
            const int ncol = nrow0 + rown;
            const int h = ncol >> 6, hd = ncol & 63;
            bf16x8 v;
            v[0] = lo[0]; v[1] = lo[1]; v[2] = lo[2]; v[3] = lo[3];
            v[4] = hi[0]; v[5] = hi[1]; v[6] = hi[2]; v[7] = hi[3];
            *(bf16x8*)(vto + ((size_t)(bidx * 8 + h) * 64 + hd) * 2048
                       + sbase + seg * 8) = v;
        }
    }
#undef STAGE_PROJ
}

// ---------------------------------------------------------------------------
// Kernel 2 (was 3): dual-stream flash attention + fused GroupNorm partial
// stats. [REVERTED to round-7 version — best measured 55.8us: (qp,st,kg)
// decomposition, 2-buffer LDS + __syncthreads, swizzles, exp2, XCD remap.]
// ---------------------------------------------------------------------------
__global__ __launch_bounds__(512, 4) void attn_kernel(
    const bf16* __restrict__ q1, const bf16* __restrict__ k1,
    const bf16* __restrict__ q2, const bf16* __restrict__ k2,
    const bf16* __restrict__ vt,
    const float* __restrict__ lq1, const float* __restrict__ lk1,
    const float* __restrict__ lq2, const float* __restrict__ lk2,
    bf16* __restrict__ o, float* __restrict__ stats)
{
    __shared__ __align__(16) bf16 smem[2][12288];   // 48 KB: 2 x (K1 | K2 | V)
    __shared__ float lbuf[8][2][16];
    __shared__ float sred[2][2];

    const int tid = threadIdx.x;
    const int wave = tid >> 6;
    const int lane = tid & 63;
    const int l15 = lane & 15, quad = lane >> 4;
    const int kg = wave >> 2;         // key group (0: keys 0..1023, 1: 1024..)
    const int w4 = wave & 3;
    const int qp = w4 & 1;            // q-pair: tiles {2qp, 2qp+1}
    const int st = w4 >> 1;           // stream: 0 -> (q1,k1), 1 -> (q2,k2)

    // XCD-aware remap (512 = 8 XCDs x 64, bijective).
    const int rid = (blockIdx.x & 7) * 64 + (blockIdx.x >> 3);
    const int bh = rid >> 5;
    const int qt = rid & 31;
    const int b = bh >> 3, h = bh & 7;

    const bf16* k1t = k1 + (size_t)bh * 2048 * 64;
    const bf16* k2t = k2 + (size_t)bh * 2048 * 64;
    const bf16* vtt = vt + (size_t)bh * 64 * 2048;

    // Q fragments for this wave's stream, 2 q-tiles (rows qp*32 .. qp*32+31).
    const bf16* qs = st ? q2 : q1;
    const int qrowA = qt * 64 + qp * 32 + l15;
    const bf16* qpA = qs + ((size_t)bh * 2048 + qrowA) * 64 + quad * 8;
    const bf16x8 qA0 = *(const bf16x8*)(qpA);
    const bf16x8 qA1 = *(const bf16x8*)(qpA + 32);
    const bf16x8 qB0 = *(const bf16x8*)(qpA + 16 * 64);
    const bf16x8 qB1 = *(const bf16x8*)(qpA + 16 * 64 + 32);

    // Staging: identical to r1 (contents independent of wave->work mapping).
    const int sw = wave & 3;
    const int skey0 = (wave < 4) ? 0 : 1024;
    const size_t ksrc0 = (size_t)(skey0 + sw * 8 + (lane >> 3)) * 64
                       + 8 * ((lane & 7) ^ (lane >> 3));
    const size_t vsrc0 = (size_t)(sw * 16 + (lane >> 2)) * 2048 + skey0 + (lane & 3) * 8;

#define STAGE_ATTN(buf, itv) do {                                   \
    const size_t koff_ = ksrc0 + (size_t)(itv) * 32 * 64;           \
    gload_lds16(k1t + koff_, (buf) + wave * 512);                   \
    gload_lds16(k2t + koff_, (buf) + 4096 + wave * 512);            \
    gload_lds16(vtt + vsrc0 + (itv) * 32, (buf) + 8192 + wave * 512); \
} while (0)

    const int koffa = 8 * (quad ^ (l15 & 7));
    const int koffb = 8 * ((quad + 4) ^ (l15 & 7));
    const int vsw = 8 * (quad ^ ((l15 >> 1) & 3));   // matches proj's xh perm

    f32x4 OA[4], OB[4];
    float lA = 0.f, lB = 0.f;
#pragma unroll
    for (int t = 0; t < 4; ++t) {
        OA[t] = (f32x4){0.f, 0.f, 0.f, 0.f};
        OB[t] = (f32x4){0.f, 0.f, 0.f, 0.f};
    }

    STAGE_ATTN(smem[0], 0);
    __syncthreads();

    for (int it = 0; it < 32; ++it) {
        const bf16* sb = smem[it & 1];
        if (it < 31) STAGE_ATTN(smem[(it & 1) ^ 1], it + 1);

        // This wave reads ONLY its stream's K (4 reads) + V (4 reads).
        const bf16* kr = sb + st * 4096 + kg * 2048;
        const bf16* vr = sb + 8192 + kg * 2048;

        const bf16x8 kt0a = *(const bf16x8*)(kr + l15 * 64 + koffa);
        const bf16x8 kt0b = *(const bf16x8*)(kr + l15 * 64 + koffb);
        const bf16x8 kt1a = *(const bf16x8*)(kr + (16 + l15) * 64 + koffa);
        const bf16x8 kt1b = *(const bf16x8*)(kr + (16 + l15) * 64 + koffb);
        const bf16x8 v0 = *(const bf16x8*)(vr + l15 * 32 + vsw);
        const bf16x8 v1 = *(const bf16x8*)(vr + (16 + l15) * 32 + vsw);
        const bf16x8 v2 = *(const bf16x8*)(vr + (32 + l15) * 32 + vsw);
        const bf16x8 v3 = *(const bf16x8*)(vr + (48 + l15) * 32 + vsw);

        const f32x4 z = (f32x4){0.f, 0.f, 0.f, 0.f};
        __builtin_amdgcn_s_setprio(1);
        f32x4 sA0 = MFMA16(kt0a, qA0, z);  sA0 = MFMA16(kt0b, qA1, sA0);
        f32x4 sA1 = MFMA16(kt1a, qA0, z);  sA1 = MFMA16(kt1b, qA1, sA1);
        f32x4 sB0 = MFMA16(kt0a, qB0, z);  sB0 = MFMA16(kt0b, qB1, sB0);
        f32x4 sB1 = MFMA16(kt1a, qB0, z);  sB1 = MFMA16(kt1b, qB1, sB1);
        __builtin_amdgcn_s_setprio(0);

        bf16x8 bA, bB;
#pragma unroll
        for (int r = 0; r < 4; ++r) {
            float e;
            e = __builtin_amdgcn_exp2f(sA0[r]); lA += e; bA[r]     = (bf16)e;
            e = __builtin_amdgcn_exp2f(sA1[r]); lA += e; bA[4 + r] = (bf16)e;
            e = __builtin_amdgcn_exp2f(sB0[r]); lB += e; bB[r]     = (bf16)e;
            e = __builtin_amdgcn_exp2f(sB1[r]); lB += e; bB[4 + r] = (bf16)e;
        }

        __builtin_amdgcn_s_setprio(1);
        OA[0] = MFMA16(v0, bA, OA[0]);
        OA[1] = MFMA16(v1, bA, OA[1]);
        OA[2] = MFMA16(v2, bA, OA[2]);
        OA[3] = MFMA16(v3, bA, OA[3]);
        OB[0] = MFMA16(v0, bB, OB[0]);
        OB[1] = MFMA16(v1, bB, OB[1]);
        OB[2] = MFMA16(v2, bB, OB[2]);
        OB[3] = MFMA16(v3, bB, OB[3]);
        __builtin_amdgcn_s_setprio(0);

        __syncthreads();
    }

    // Quad-replica reduce of l, publish per-wave partial l.
    lA += __shfl_xor(lA, 16, 64);  lA += __shfl_xor(lA, 32, 64);
    lB += __shfl_xor(lB, 16, 64);  lB += __shfl_xor(lB, 32, 64);
    if (lane < 16) {
        lbuf[wave][0][lane] = lA;
        lbuf[wave][1][lane] = lB;
    }
    __syncthreads();

    // Stage 1: kg-combine. kg=1 waves export OA,OB; kg=0 waves accumulate.
    f32x4* rb = (f32x4*)smem;                     // 3072 f32x4 available
    if (kg == 1) {
        f32x4* dst = rb + w4 * 512;
#pragma unroll
        for (int t = 0; t < 4; ++t) {
            dst[t * 64 + lane]       = OA[t];
            dst[(4 + t) * 64 + lane] = OB[t];
        }
    }
    __syncthreads();
    if (kg == 0) {
        const f32x4* src = rb + w4 * 512;
#pragma unroll
        for (int t = 0; t < 4; ++t) {
            OA[t] += src[t * 64 + lane];
            OB[t] += src[(4 + t) * 64 + lane];
        }
    }
    __syncthreads();

    // Stage 2: stream-combine. kg=0,st=1 waves (2,3) export full-key O2.
    if (kg == 0 && st == 1) {
        f32x4* dst = rb + qp * 512;
#pragma unroll
        for (int t = 0; t < 4; ++t) {
            dst[t * 64 + lane]       = OA[t];
            dst[(4 + t) * 64 + lane] = OB[t];
        }
    }
    __syncthreads();

    float ssum = 0.f, ssq = 0.f;
    if (kg == 0 && st == 0) {                     // waves 0,1: final combine
        const f32x4* src = rb + qp * 512;         // stream-2 full-key O
        const float L1A = lA + lbuf[4 + qp][0][l15];
        const float L1B = lB + lbuf[4 + qp][1][l15];
        const float L2A = lbuf[2 + qp][0][l15] + lbuf[6 + qp][0][l15];
        const float L2B = lbuf[2 + qp][1][l15] + lbuf[6 + qp][1][l15];
        const float lam = __expf(lq1[h] * lk1[h]) - __expf(lq2[h] * lk2[h]) + LAMBDA_INIT;
        const float i1A = 1.f / L1A, i2A = lam / L2A;
        const float i1B = 1.f / L1B, i2B = lam / L2B;
        const size_t rowA = (size_t)(b * 2048 + qt * 64 + qp * 32 + l15) * 512 + h * 64;
        const size_t rowB = rowA + 16 * 512;
#pragma unroll
        for (int t = 0; t < 4; ++t) {
            const f32x4 o2A = src[t * 64 + lane];
            const f32x4 o2B = src[(4 + t) * 64 + lane];
#pragma unroll
            for (int r = 0; r < 4; ++r) {
                const float vA = OA[t][r] * i1A - o2A[r] * i2A;
                const float vB = OB[t][r] * i1B - o2B[r] * i2B;
                ssum += vA + vB;
                ssq += vA * vA + vB * vB;
                o[rowA + t * 16 + quad * 4 + r] = (bf16)vA;
                o[rowB + t * 16 + quad * 4 + r] = (bf16)vB;
            }
        }
    }
#pragma unroll
    for (int off = 1; off < 64; off <<= 1) {
        ssum += __shfl_xor(ssum, off, 64);
        ssq += __shfl_xor(ssq, off, 64);
    }
    if (kg == 0 && st == 0 && lane == 0) { sred[qp][0] = ssum; sred[qp][1] = ssq; }
    __syncthreads();
    if (tid == 0) {
        const float s0 = sred[0][0] + sred[1][0];
        const float s1 = sred[0][1] + sred[1][1];
        const int bg = b * 4 + (h >> 1);
        atomicAdd(&stats[bg * 2], s0);
        atomicAdd(&stats[bg * 2 + 1], s1);
    }
#undef STAGE_ATTN
}

// ---------------------------------------------------------------------------
// Kernel 3 (was 4): output GEMM with GN folded. Now also absorbs prep's
// owg/S0: B-panel reg-staged from ow f32 with the gnw multiply inline;
// S0[n] = sum_c gnb[c]*ow[n,c] accumulated during the K-loop (each block
// traverses all 512 c for its 64 rows) and 8-lane-reduced into LDS.
// Back to simple 2-buffer __syncthreads (mixed gload/ds_write staging).
// ---------------------------------------------------------------------------
__global__ __launch_bounds__(256) void out_gemm_kernel(
    const bf16* __restrict__ o, const float* __restrict__ ow,
    const float* __restrict__ gnw, const float* __restrict__ gnb,
    const float* __restrict__ stats, const float* __restrict__ ob,
    float* __restrict__ y)
{
    __shared__ __align__(16) bf16 sh[16384];   // 32 KB: As[2]|Bs[2]; reused as Tf
    __shared__ float s0l[64];
    bf16* const As0 = sh;
    bf16* const As1 = sh + 4096;
    bf16* const Bs0 = sh + 8192;
    bf16* const Bs1 = sh + 12288;

    const int tid = threadIdx.x;
    const int wave = tid >> 6, lane = tid & 63;
    const int l15 = lane & 15, quad = lane >> 4;

    // XCD swizzle: 512 blocks = 8 XCDs x 64.
    const int swzb = (blockIdx.x & 7) * 64 + (blockIdx.x >> 3);
    const int mb = swzb >> 3;
    const int nb = swzb & 7;
    const int b = mb >> 5;

    const float N = 128.f * 2048.f;
    float mu[4], rs[4];
#pragma unroll
    for (int g = 0; g < 4; ++g) {
        const float m = stats[(b * 4 + g) * 2] / N;
        const float var = stats[(b * 4 + g) * 2 + 1] / N - m * m;
        mu[g] = m;
        rs[g] = rsqrtf(var + EPS);
    }

    const int srow = lane >> 3;                   // 0..7
    const int scol = 8 * ((lane & 7) ^ srow);     // swizzled source col
    const bf16* ag = o + (size_t)(mb * 64 + srow) * 512 + scol;
    const float* bgf = ow + (size_t)(nb * 64 + srow) * 512 + scol;

    float s0a = 0.f, s0b = 0.f;                   // S0 partials (chunk 0/1)

    // A: gload_lds (bf16 source). B: reg-stage ow f32 * gnw -> bf16, and
    // accumulate gnb-weighted partials for S0.
#define STAGE_OUT(abuf, bbuf, s) do {                                          \
    const int k0_ = (s) * 64;                                                  \
    const f32x4 gv0 = *(const f32x4*)(gnw + k0_ + scol);                       \
    const f32x4 gv1 = *(const f32x4*)(gnw + k0_ + scol + 4);                   \
    const f32x4 nb0 = *(const f32x4*)(gnb + k0_ + scol);                       \
    const f32x4 nb1 = *(const f32x4*)(gnb + k0_ + scol + 4);                   \
    gload_lds16(ag + (size_t)((wave * 2) * 8) * 512 + k0_,                     \
                (abuf) + (wave * 2) * 512);                                    \
    gload_lds16(ag + (size_t)((wave * 2 + 1) * 8) * 512 + k0_,                 \
                (abuf) + (wave * 2 + 1) * 512);                                \
    {                                                                          \
        const float* p = bgf + (size_t)((wave * 2) * 8) * 512 + k0_;           \
        const f32x4 w0 = *(const f32x4*)p;                                     \
        const f32x4 w1 = *(const f32x4*)(p + 4);                               \
        bf16x8 bv;                                                             \
        _Pragma("unroll")                                                      \
        for (int j_ = 0; j_ < 4; ++j_) {                                       \
            bv[j_]     = (bf16)(w0[j_] * gv0[j_]);                             \
            bv[4 + j_] = (bf16)(w1[j_] * gv1[j_]);                             \
            s0a += nb0[j_] * w0[j_] + nb1[j_] * w1[j_];                        \
        }                                                                      \
        *(bf16x8*)((bbuf) + (wave * 2) * 512 + lane * 8) = bv;                 \
    }                                                                          \
    {                                                                          \
        const float* p = bgf + (size_t)((wave * 2 + 1) * 8) * 512 + k0_;       \
        const f32x4 w0 = *(const f32x4*)p;                                     \
        const f32x4 w1 = *(const f32x4*)(p + 4);                               \
        bf16x8 bv;                                                             \
        _Pragma("unroll")                                                      \
        for (int j_ = 0; j_ < 4; ++j_) {                                       \
            bv[j_]     = (bf16)(w0[j_] * gv0[j_]);                             \
            bv[4 + j_] = (bf16)(w1[j_] * gv1[j_]);                             \
            s0b += nb0[j_] * w0[j_] + nb1[j_] * w1[j_];                        \
        }                                                                      \
        *(bf16x8*)((bbuf) + (wave * 2 + 1) * 512 + lane * 8) = bv;             \
    }                                                                          \
} while (0)

    f32x4 acc[4], tot[4];
#pragma unroll
    for (int i = 0; i < 4; ++i) {
        acc[i] = (f32x4){0.f, 0.f, 0.f, 0.f};
        tot[i] = (f32x4){0.f, 0.f, 0.f, 0.f};
    }
    float s1g[4];
    float s1p = 0.f;
#pragma unroll
    for (int g = 0; g < 4; ++g) s1g[g] = 0.f;

    STAGE_OUT(As0, Bs0, 0);
    __syncthreads();

    const int ka = 8 * (quad ^ (l15 & 7));

    for (int kk = 0; kk < 8; ++kk) {
        const bf16* Ac = (kk & 1) ? As1 : As0;
        const bf16* Bc = (kk & 1) ? Bs1 : Bs0;
        if (kk < 7) {
            if (kk & 1) STAGE_OUT(As0, Bs0, kk + 1);
            else        STAGE_OUT(As1, Bs1, kk + 1);
        }

        bf16x8 al[4], ah[4];
#pragma unroll
        for (int i = 0; i < 4; ++i) {
            const bf16* p = Ac + (i * 16 + l15) * 64;
            al[i] = *(const bf16x8*)(p + ka);
            ah[i] = *(const bf16x8*)(p + (ka ^ 32));
        }
        const bf16* pb = Bc + (wave * 16 + l15) * 64;
        const bf16x8 bl = *(const bf16x8*)(pb + ka);
        const bf16x8 bh = *(const bf16x8*)(pb + (ka ^ 32));

#pragma unroll
        for (int i = 0; i < 4; ++i) {
            acc[i] = MFMA16(al[i], bl, acc[i]);
            acc[i] = MFMA16(ah[i], bh, acc[i]);
        }

#pragma unroll
        for (int j = 0; j < 8; ++j) s1p += (float)bl[j] + (float)bh[j];

        __syncthreads();

        if (kk & 1) {
            const int g = kk >> 1;
#pragma unroll
            for (int i = 0; i < 4; ++i) {
#pragma unroll
                for (int r = 0; r < 4; ++r) tot[i][r] += rs[g] * acc[i][r];
                acc[i] = (f32x4){0.f, 0.f, 0.f, 0.f};
            }
            float sg = s1p + __shfl_xor(s1p, 16, 64);
            sg += __shfl_xor(sg, 32, 64);
            s1g[g] = sg;
            s1p = 0.f;
        }
    }

    // S0 finish: 8-lane group reduce (lanes sharing a staged row differ only
    // in lane bits 0..2), then publish per-row sums.
    s0a += __shfl_xor(s0a, 1, 64); s0a += __shfl_xor(s0a, 2, 64); s0a += __shfl_xor(s0a, 4, 64);
    s0b += __shfl_xor(s0b, 1, 64); s0b += __shfl_xor(s0b, 2, 64); s0b += __shfl_xor(s0b, 4, 64);
    if ((lane & 7) == 0) {
        s0l[(wave * 2) * 8 + srow]     = s0a;
        s0l[(wave * 2 + 1) * 8 + srow] = s0b;
    }
    __syncthreads();

    const int nl = wave * 16 + l15;
    const int ncol = nb * 64 + nl;
    float bias = s0l[nl] + ob[ncol];
#pragma unroll
    for (int g = 0; g < 4; ++g) bias -= mu[g] * rs[g] * s1g[g];

    // LDS-staged epilogue: Tf[m][n ^ (quad(m)<<4)] f32, then coalesced rows.
    float* const Tf = (float*)sh;                 // 64x64 f32 = 16 KB
#pragma unroll
    for (int i = 0; i < 4; ++i) {
        const int mbase = i * 16 + quad * 4;
#pragma unroll
        for (int r = 0; r < 4; ++r)
            Tf[(mbase + r) * 64 + (nl ^ (quad << 4))] = tot[i][r] + bias;
    }
    __syncthreads();

#pragma unroll
    for (int ps = 0; ps < 4; ++ps) {
        const int idx = (ps * 256 + tid) * 4;     // 0..4095
        const int m = idx >> 6, n4 = idx & 63;
        const f32x4 v = *(const f32x4*)(Tf + m * 64 + (n4 ^ (((m >> 2) & 3) << 4)));
        *(f32x4*)(y + (size_t)(mb * 64 + m) * 512 + nb * 64 + n4) = v;
    }
#undef STAGE_OUT
}

// ---------------------------------------------------------------------------
extern "C" void kernel_launch(void* const* d_in, const int* in_sizes, int n_in,
                              void* d_out, int out_size, void* d_ws, size_t ws_size,
                              hipStream_t stream)
{
    const float* x   = (const float*)d_in[0];
    const float* K1w = (const float*)d_in[1];
    const float* K1b = (const float*)d_in[2];
    const float* Q1w = (const float*)d_in[3];
    const float* K2w = (const float*)d_in[4];
    const float* K2b = (const float*)d_in[5];
    const float* Q2w = (const float*)d_in[6];
    const float* Vw  = (const float*)d_in[7];
    const float* lq1 = (const float*)d_in[8];
    const float* lk1 = (const float*)d_in[9];
    const float* lq2 = (const float*)d_in[10];
    const float* lk2 = (const float*)d_in[11];
    const float* gnw = (const float*)d_in[12];
    const float* gnb = (const float*)d_in[13];
    const float* Ow  = (const float*)d_in[14];
    const float* Ob  = (const float*)d_in[15];

    const size_t SZ = (size_t)2 * 8 * 2048 * 64;   // 2M elements per tensor
    bf16* q1 = (bf16*)d_ws;
    bf16* k1 = q1 + SZ;
    bf16* q2 = k1 + SZ;
    bf16* k2 = q2 + SZ;
    bf16* vt = k2 + SZ;
    bf16* o  = vt + SZ;                 // attn output
    float* stats = (float*)(o + SZ);

    proj_kernel<<<640, 256, 0, stream>>>(x, Q1w, K1w, Q2w, K2w, Vw,
                                         K1b, K2b, q1, k1, q2, k2, vt, stats);
    attn_kernel<<<512, 512, 0, stream>>>(q1, k1, q2, k2, vt,
                                         lq1, lk1, lq2, lk2, o, stats);
    out_gemm_kernel<<<512, 256, 0, stream>>>(o, Ow, gnw, gnb, stats, Ob,
                                             (float*)d_out);
}

// Round 10
// 169.663 us; speedup vs baseline: 1.6099x; 1.0652x over previous
//
#include <hip/hip_runtime.h>
#include <hip/hip_bf16.h>

typedef __bf16 bf16;
typedef __attribute__((ext_vector_type(4))) __bf16 bf16x4;
typedef __attribute__((ext_vector_type(8))) __bf16 bf16x8;
typedef __attribute__((ext_vector_type(4))) float f32x4;

#define MFMA16(a, b, c) __builtin_amdgcn_mfma_f32_16x16x32_bf16((a), (b), (c), 0, 0, 0)

// B=2, S=2048, D=512, H=8, hd=64, G=4. All I/O float32; bf16 MFMA compute.
static constexpr float EPS = 1e-5f;
static constexpr float LAMBDA_INIT = 0.2f;
static constexpr float LOG2E = 1.44269504088896340736f;

// Load 8 consecutive f32 (32B, 16B-aligned) and convert to bf16x8.
__device__ __forceinline__ bf16x8 cvt8(const float* p) {
    const f32x4 a = *(const f32x4*)p;
    const f32x4 b = *(const f32x4*)(p + 4);
    bf16x8 r;
    r[0] = (bf16)a[0]; r[1] = (bf16)a[1]; r[2] = (bf16)a[2]; r[3] = (bf16)a[3];
    r[4] = (bf16)b[0]; r[5] = (bf16)b[1]; r[6] = (bf16)b[2]; r[7] = (bf16)b[3];
    return r;
}

// Async 16B global -> LDS (lane i lands at lds_base + i*16; base wave-uniform).
__device__ __forceinline__ void gload_lds16(const void* g, void* l) {
    __builtin_amdgcn_global_load_lds(
        (const __attribute__((address_space(1))) unsigned int*)g,
        (__attribute__((address_space(3))) unsigned int*)l,
        16, 0, 0);
}

// ---------------------------------------------------------------------------
// Kernel 1: combined cvt + prep. GN section rewritten wave-parallel:
// one wave per 4 rows, f32x4 loads, pure shuffle reduce, ZERO barriers
// (was: 16 serial rounds x 2 __syncthreads).
// ---------------------------------------------------------------------------
__global__ __launch_bounds__(256) void prep_kernel(
    const float* __restrict__ x,
    const float* __restrict__ q1w, const float* __restrict__ k1w,
    const float* __restrict__ q2w, const float* __restrict__ k2w,
    const float* __restrict__ vw,
    const float* __restrict__ ow, const float* __restrict__ gnw,
    const float* __restrict__ gnb,
    bf16* __restrict__ xb, bf16* __restrict__ wb,
    bf16* __restrict__ owg, float* __restrict__ S0, float* __restrict__ stats)
{
    const int tid = threadIdx.x;
    if (blockIdx.x < 1664) {
        const size_t base = ((size_t)blockIdx.x * 256 + tid) * 8;
        if (base < 2097152) {                    // x: 2*2048*512
            *(bf16x8*)(xb + base) = cvt8(x + base);
        } else {
            const size_t wbase = base - 2097152; // 0..1310720 (5 x 262144)
            const int wsel = (int)(wbase >> 18);
            const size_t off = wbase & 262143;
            const float* W = (wsel == 0) ? q1w : (wsel == 1) ? k1w :
                             (wsel == 2) ? q2w : (wsel == 3) ? k2w : vw;
            *(bf16x8*)(wb + wbase) = cvt8(W + off);
        }
        return;
    }

    const int pb = blockIdx.x - 1664;            // 0..31
    if (pb == 0 && tid < 16) stats[tid] = 0.f;

    const int wave = tid >> 6, lane = tid & 63;
    const int c0 = lane * 8;                     // 8 cols per lane
    const f32x4 gw0 = *(const f32x4*)(gnw + c0);
    const f32x4 gw1 = *(const f32x4*)(gnw + c0 + 4);
    const f32x4 gb0 = *(const f32x4*)(gnb + c0);
    const f32x4 gb1 = *(const f32x4*)(gnb + c0 + 4);

#pragma unroll
    for (int rr = 0; rr < 4; ++rr) {
        const int n = pb * 16 + wave * 4 + rr;
        const float* p = ow + (size_t)n * 512 + c0;
        const f32x4 w0 = *(const f32x4*)p;
        const f32x4 w1 = *(const f32x4*)(p + 4);
        bf16x8 og;
        float s = 0.f;
#pragma unroll
        for (int j = 0; j < 4; ++j) {
            og[j]     = (bf16)(w0[j] * gw0[j]);
            og[4 + j] = (bf16)(w1[j] * gw1[j]);
            s += gb0[j] * w0[j] + gb1[j] * w1[j];
        }
        *(bf16x8*)(owg + (size_t)n * 512 + c0) = og;
#pragma unroll
        for (int off = 1; off < 64; off <<= 1) s += __shfl_xor(s, off, 64);
        if (lane == 0) S0[n] = s;
    }
}

// ---------------------------------------------------------------------------
// Kernel 2: fused QKV projection GEMM. [reverted to round-7 best: bf16
// xb/wb inputs, gload_lds staging, BK=64 XOR swizzle, 2-phase dbuf,
// XCD swizzle (640 = 8 x 80), LDS-staged epilogues]
// ---------------------------------------------------------------------------
__global__ __launch_bounds__(256) void proj_kernel(
    const bf16* __restrict__ xb, const bf16* __restrict__ wb,
    const float* __restrict__ k1b, const float* __restrict__ k2b,
    bf16* __restrict__ q1o, bf16* __restrict__ k1o,
    bf16* __restrict__ q2o, bf16* __restrict__ k2o,
    bf16* __restrict__ vto)
{
    __shared__ __align__(16) bf16 sh[32768];   // 64 KB: As[2]|Bs[2]; reused as T
    bf16* const As0 = sh;
    bf16* const As1 = sh + 8192;
    bf16* const Bs0 = sh + 16384;
    bf16* const Bs1 = sh + 24576;

    const int tid = threadIdx.x;
    const int wave = tid >> 6, lane = tid & 63;
    const int l15 = lane & 15, quad = lane >> 4;
    const int wm = wave >> 1, wn = wave & 1;

    // XCD swizzle: 640 blocks = 8 XCDs x 80.
    const int swzb = (blockIdx.x & 7) * 80 + (blockIdx.x >> 3);
    const int mb = swzb / 20;
    const int nb = swzb % 20;
    const int wsel = nb >> 2;
    const int nrow0 = (nb & 3) * 128;

    const int srow = lane >> 3;                   // 0..7 row within chunk
    const int scol = 8 * ((lane & 7) ^ srow);     // swizzled source col
    const bf16* ag = xb + (size_t)(mb * 128 + srow) * 512 + scol;
    const bf16* bg = wb + (size_t)(wsel * 512 + nrow0 + srow) * 512 + scol;

    f32x4 acc[4][4];
#pragma unroll
    for (int i = 0; i < 4; ++i)
#pragma unroll
        for (int j = 0; j < 4; ++j)
            acc[i][j] = (f32x4){0.f, 0.f, 0.f, 0.f};

#define STAGE_PROJ(abuf, bbuf, s) do {                                         \
    const int k0_ = (s) * 64;                                                  \
    _Pragma("unroll")                                                          \
    for (int c_ = 0; c_ < 4; ++c_) {                                           \
        const int chunk_ = wave * 4 + c_;                                      \
        gload_lds16(ag + (size_t)(chunk_ * 8) * 512 + k0_, (abuf) + chunk_ * 512); \
        gload_lds16(bg + (size_t)(chunk_ * 8) * 512 + k0_, (bbuf) + chunk_ * 512); \
    }                                                                          \
} while (0)

    STAGE_PROJ(As0, Bs0, 0);
    __syncthreads();

    const int ka = 8 * (quad ^ (l15 & 7));        // k 0..31 chunk (swizzled)

    for (int s = 0; s < 8; ++s) {
        const bf16* Ac = (s & 1) ? As1 : As0;
        const bf16* Bc = (s & 1) ? Bs1 : Bs0;
        if (s < 7) {
            if (s & 1) STAGE_PROJ(As0, Bs0, s + 1);
            else       STAGE_PROJ(As1, Bs1, s + 1);
        }

        bf16x8 al[4], ah[4], bl[4], bh_[4];
#pragma unroll
        for (int i = 0; i < 4; ++i) {
            const bf16* p = Ac + (wm * 64 + i * 16 + l15) * 64;
            al[i] = *(const bf16x8*)(p + ka);
            ah[i] = *(const bf16x8*)(p + (ka ^ 32));
        }
#pragma unroll
        for (int j = 0; j < 4; ++j) {
            const bf16* p = Bc + (wn * 64 + j * 16 + l15) * 64;
            bl[j]  = *(const bf16x8*)(p + ka);
            bh_[j] = *(const bf16x8*)(p + (ka ^ 32));
        }

#pragma unroll
        for (int i = 0; i < 4; ++i)
#pragma unroll
            for (int j = 0; j < 4; ++j) {
                acc[i][j] = MFMA16(al[i], bl[j], acc[i][j]);
                acc[i][j] = MFMA16(ah[i], bh_[j], acc[i][j]);
            }

        __syncthreads();
    }

    const int bidx = mb >> 4;
    const int sbase = (mb & 15) * 128;
    const float scale = (wsel == 0 || wsel == 2) ? 0.125f * LOG2E : 1.0f;

    if (wsel != 4) {
        // ---- q/k epilogue: T[m][n ^ (quad(m)<<4)], then linear head chunks.
        bf16* const T = sh;                       // 128x128 bf16 = 32 KB
        const int swzq = quad << 4;               // (m>>2)&3 == quad here
#pragma unroll
        for (int j = 0; j < 4; ++j) {
            const int nl = wn * 64 + j * 16 + l15;
            const int ncol = nrow0 + nl;
            float bias = 0.f;
            if (wsel == 1) bias = k1b[ncol];
            if (wsel == 3) bias = k2b[ncol];
            const int nswz = nl ^ swzq;
#pragma unroll
            for (int i = 0; i < 4; ++i) {
                const int mbase = wm * 64 + i * 16 + quad * 4;
#pragma unroll
                for (int r = 0; r < 4; ++r)
                    T[(mbase + r) * 128 + nswz] = (bf16)(acc[i][j][r] * scale + bias);
            }
        }
        __syncthreads();

        bf16* const dst = (wsel == 0) ? q1o : (wsel == 1) ? k1o :
                          (wsel == 2) ? q2o : k2o;
#pragma unroll
        for (int hsel = 0; hsel < 2; ++hsel) {
            const int h = (nrow0 >> 6) + hsel;
            bf16* db = dst + ((size_t)(bidx * 8 + h) * 2048 + sbase) * 64;
#pragma unroll
            for (int ps = 0; ps < 4; ++ps) {
                const int idx = (ps * 256 + tid) * 8;     // 0..8191
                const int m = idx >> 6, hd = idx & 63;
                const bf16x8 v = *(const bf16x8*)(
                    T + m * 128 + ((hsel * 64 + hd) ^ (((m >> 2) & 3) << 4)));
                *(bf16x8*)(db + idx) = v;
            }
        }
    } else {
        // ---- V epilogue: Tt[n][sp] (pitch 132, 4-elem XOR swizzle), with the
        // period-32 s-permutation folded into the column index; then 256B rows.
        bf16* const Tt = sh;                      // 128x132 bf16 = 33 KB
#pragma unroll
        for (int j = 0; j < 4; ++j) {
            const int nl = wn * 64 + j * 16 + l15;
            const int hd = (nrow0 + nl) & 63;
            const int xh = (hd >> 1) & 3;
            const int swz = (nl & 7) << 2;
#pragma unroll
            for (int i = 0; i < 4; ++i) {
                const int colb = (wm * 64 + (i >> 1) * 32 + ((quad ^ xh) << 3)
                                  + ((i & 1) << 2)) ^ swz;
                bf16x4 pk;
#pragma unroll
                for (int r = 0; r < 4; ++r) pk[r] = (bf16)acc[i][j][r];
                *(bf16x4*)(Tt + nl * 132 + colb) = pk;
            }
        }
        __syncthreads();

#pragma unroll
        for (int ps = 0; ps < 8; ++ps) {
            const int rown = ps * 16 + (tid >> 4);        // n_local 0..127
            const int seg = tid & 15;                     // 8-elem segment
            const int swz = (rown & 7) << 2;
            const bf16x4 lo = *(const bf16x4*)(Tt + rown * 132 + ((seg * 8) ^ swz));
            const bf16x4 hi = *(const bf16x4*)(Tt + rown * 132 + ((seg * 8 + 4) ^ swz));
            const int ncol = nrow0 + rown;
            const int h = ncol >> 6, hd = ncol & 63;
            bf16x8 v;
            v[0] = lo[0]; v[1] = lo[1]; v[2] = lo[2]; v[3] = lo[3];
            v[4] = hi[0]; v[5] = hi[1]; v[6] = hi[2]; v[7] = hi[3];
            *(bf16x8*)(vto + ((size_t)(bidx * 8 + h) * 64 + hd) * 2048
                       + sbase + seg * 8) = v;
        }
    }
#undef STAGE_PROJ
}

// ---------------------------------------------------------------------------
// Kernel 3: dual-stream flash attention + fused GroupNorm partial stats.
// [round-7 best: (qp,st,kg) decomposition, 2-buffer LDS + __syncthreads,
// swizzles, exp2, XCD remap — 55.8us measured]
// ---------------------------------------------------------------------------
__global__ __launch_bounds__(512, 4) void attn_kernel(
    const bf16* __restrict__ q1, const bf16* __restrict__ k1,
    const bf16* __restrict__ q2, const bf16* __restrict__ k2,
    const bf16* __restrict__ vt,
    const float* __restrict__ lq1, const float* __restrict__ lk1,
    const float* __restrict__ lq2, const float* __restrict__ lk2,
    bf16* __restrict__ o, float* __restrict__ stats)
{
    __shared__ __align__(16) bf16 smem[2][12288];   // 48 KB: 2 x (K1 | K2 | V)
    __shared__ float lbuf[8][2][16];
    __shared__ float sred[2][2];

    const int tid = threadIdx.x;
    const int wave = tid >> 6;
    const int lane = tid & 63;
    const int l15 = lane & 15, quad = lane >> 4;
    const int kg = wave >> 2;         // key group (0: keys 0..1023, 1: 1024..)
    const int w4 = wave & 3;
    const int qp = w4 & 1;            // q-pair: tiles {2qp, 2qp+1}
    const int st = w4 >> 1;           // stream: 0 -> (q1,k1), 1 -> (q2,k2)

    // XCD-aware remap (512 = 8 XCDs x 64, bijective).
    const int rid = (blockIdx.x & 7) * 64 + (blockIdx.x >> 3);
    const int bh = rid >> 5;
    const int qt = rid & 31;
    const int b = bh >> 3, h = bh & 7;

    const bf16* k1t = k1 + (size_t)bh * 2048 * 64;
    const bf16* k2t = k2 + (size_t)bh * 2048 * 64;
    const bf16* vtt = vt + (size_t)bh * 64 * 2048;

    // Q fragments for this wave's stream, 2 q-tiles (rows qp*32 .. qp*32+31).
    const bf16* qs = st ? q2 : q1;
    const int qrowA = qt * 64 + qp * 32 + l15;
    const bf16* qpA = qs + ((size_t)bh * 2048 + qrowA) * 64 + quad * 8;
    const bf16x8 qA0 = *(const bf16x8*)(qpA);
    const bf16x8 qA1 = *(const bf16x8*)(qpA + 32);
    const bf16x8 qB0 = *(const bf16x8*)(qpA + 16 * 64);
    const bf16x8 qB1 = *(const bf16x8*)(qpA + 16 * 64 + 32);

    // Staging: contents independent of wave->work mapping.
    const int sw = wave & 3;
    const int skey0 = (wave < 4) ? 0 : 1024;
    const size_t ksrc0 = (size_t)(skey0 + sw * 8 + (lane >> 3)) * 64
                       + 8 * ((lane & 7) ^ (lane >> 3));
    const size_t vsrc0 = (size_t)(sw * 16 + (lane >> 2)) * 2048 + skey0 + (lane & 3) * 8;

#define STAGE_ATTN(buf, itv) do {                                   \
    const size_t koff_ = ksrc0 + (size_t)(itv) * 32 * 64;           \
    gload_lds16(k1t + koff_, (buf) + wave * 512);                   \
    gload_lds16(k2t + koff_, (buf) + 4096 + wave * 512);            \
    gload_lds16(vtt + vsrc0 + (itv) * 32, (buf) + 8192 + wave * 512); \
} while (0)

    const int koffa = 8 * (quad ^ (l15 & 7));
    const int koffb = 8 * ((quad + 4) ^ (l15 & 7));
    const int vsw = 8 * (quad ^ ((l15 >> 1) & 3));   // matches proj's xh perm

    f32x4 OA[4], OB[4];
    float lA = 0.f, lB = 0.f;
#pragma unroll
    for (int t = 0; t < 4; ++t) {
        OA[t] = (f32x4){0.f, 0.f, 0.f, 0.f};
        OB[t] = (f32x4){0.f, 0.f, 0.f, 0.f};
    }

    STAGE_ATTN(smem[0], 0);
    __syncthreads();

    for (int it = 0; it < 32; ++it) {
        const bf16* sb = smem[it & 1];
        if (it < 31) STAGE_ATTN(smem[(it & 1) ^ 1], it + 1);

        // This wave reads ONLY its stream's K (4 reads) + V (4 reads).
        const bf16* kr = sb + st * 4096 + kg * 2048;
        const bf16* vr = sb + 8192 + kg * 2048;

        const bf16x8 kt0a = *(const bf16x8*)(kr + l15 * 64 + koffa);
        const bf16x8 kt0b = *(const bf16x8*)(kr + l15 * 64 + koffb);
        const bf16x8 kt1a = *(const bf16x8*)(kr + (16 + l15) * 64 + koffa);
        const bf16x8 kt1b = *(const bf16x8*)(kr + (16 + l15) * 64 + koffb);
        const bf16x8 v0 = *(const bf16x8*)(vr + l15 * 32 + vsw);
        const bf16x8 v1 = *(const bf16x8*)(vr + (16 + l15) * 32 + vsw);
        const bf16x8 v2 = *(const bf16x8*)(vr + (32 + l15) * 32 + vsw);
        const bf16x8 v3 = *(const bf16x8*)(vr + (48 + l15) * 32 + vsw);

        const f32x4 z = (f32x4){0.f, 0.f, 0.f, 0.f};
        __builtin_amdgcn_s_setprio(1);
        f32x4 sA0 = MFMA16(kt0a, qA0, z);  sA0 = MFMA16(kt0b, qA1, sA0);
        f32x4 sA1 = MFMA16(kt1a, qA0, z);  sA1 = MFMA16(kt1b, qA1, sA1);
        f32x4 sB0 = MFMA16(kt0a, qB0, z);  sB0 = MFMA16(kt0b, qB1, sB0);
        f32x4 sB1 = MFMA16(kt1a, qB0, z);  sB1 = MFMA16(kt1b, qB1, sB1);
        __builtin_amdgcn_s_setprio(0);

        bf16x8 bA, bB;
#pragma unroll
        for (int r = 0; r < 4; ++r) {
            float e;
            e = __builtin_amdgcn_exp2f(sA0[r]); lA += e; bA[r]     = (bf16)e;
            e = __builtin_amdgcn_exp2f(sA1[r]); lA += e; bA[4 + r] = (bf16)e;
            e = __builtin_amdgcn_exp2f(sB0[r]); lB += e; bB[r]     = (bf16)e;
            e = __builtin_amdgcn_exp2f(sB1[r]); lB += e; bB[4 + r] = (bf16)e;
        }

        __builtin_amdgcn_s_setprio(1);
        OA[0] = MFMA16(v0, bA, OA[0]);
        OA[1] = MFMA16(v1, bA, OA[1]);
        OA[2] = MFMA16(v2, bA, OA[2]);
        OA[3] = MFMA16(v3, bA, OA[3]);
        OB[0] = MFMA16(v0, bB, OB[0]);
        OB[1] = MFMA16(v1, bB, OB[1]);
        OB[2] = MFMA16(v2, bB, OB[2]);
        OB[3] = MFMA16(v3, bB, OB[3]);
        __builtin_amdgcn_s_setprio(0);

        __syncthreads();
    }

    // Quad-replica reduce of l, publish per-wave partial l.
    lA += __shfl_xor(lA, 16, 64);  lA += __shfl_xor(lA, 32, 64);
    lB += __shfl_xor(lB, 16, 64);  lB += __shfl_xor(lB, 32, 64);
    if (lane < 16) {
        lbuf[wave][0][lane] = lA;
        lbuf[wave][1][lane] = lB;
    }
    __syncthreads();

    // Stage 1: kg-combine. kg=1 waves export OA,OB; kg=0 waves accumulate.
    f32x4* rb = (f32x4*)smem;                     // 3072 f32x4 available
    if (kg == 1) {
        f32x4* dst = rb + w4 * 512;
#pragma unroll
        for (int t = 0; t < 4; ++t) {
            dst[t * 64 + lane]       = OA[t];
            dst[(4 + t) * 64 + lane] = OB[t];
        }
    }
    __syncthreads();
    if (kg == 0) {
        const f32x4* src = rb + w4 * 512;
#pragma unroll
        for (int t = 0; t < 4; ++t) {
            OA[t] += src[t * 64 + lane];
            OB[t] += src[(4 + t) * 64 + lane];
        }
    }
    __syncthreads();

    // Stage 2: stream-combine. kg=0,st=1 waves (2,3) export full-key O2.
    if (kg == 0 && st == 1) {
        f32x4* dst = rb + qp * 512;
#pragma unroll
        for (int t = 0; t < 4; ++t) {
            dst[t * 64 + lane]       = OA[t];
            dst[(4 + t) * 64 + lane] = OB[t];
        }
    }
    __syncthreads();

    float ssum = 0.f, ssq = 0.f;
    if (kg == 0 && st == 0) {                     // waves 0,1: final combine
        const f32x4* src = rb + qp * 512;         // stream-2 full-key O
        const float L1A = lA + lbuf[4 + qp][0][l15];
        const float L1B = lB + lbuf[4 + qp][1][l15];
        const float L2A = lbuf[2 + qp][0][l15] + lbuf[6 + qp][0][l15];
        const float L2B = lbuf[2 + qp][1][l15] + lbuf[6 + qp][1][l15];
        const float lam = __expf(lq1[h] * lk1[h]) - __expf(lq2[h] * lk2[h]) + LAMBDA_INIT;
        const float i1A = 1.f / L1A, i2A = lam / L2A;
        const float i1B = 1.f / L1B, i2B = lam / L2B;
        const size_t rowA = (size_t)(b * 2048 + qt * 64 + qp * 32 + l15) * 512 + h * 64;
        const size_t rowB = rowA + 16 * 512;
#pragma unroll
        for (int t = 0; t < 4; ++t) {
            const f32x4 o2A = src[t * 64 + lane];
            const f32x4 o2B = src[(4 + t) * 64 + lane];
#pragma unroll
            for (int r = 0; r < 4; ++r) {
                const float vA = OA[t][r] * i1A - o2A[r] * i2A;
                const float vB = OB[t][r] * i1B - o2B[r] * i2B;
                ssum += vA + vB;
                ssq += vA * vA + vB * vB;
                o[rowA + t * 16 + quad * 4 + r] = (bf16)vA;
                o[rowB + t * 16 + quad * 4 + r] = (bf16)vB;
            }
        }
    }
#pragma unroll
    for (int off = 1; off < 64; off <<= 1) {
        ssum += __shfl_xor(ssum, off, 64);
        ssq += __shfl_xor(ssq, off, 64);
    }
    if (kg == 0 && st == 0 && lane == 0) { sred[qp][0] = ssum; sred[qp][1] = ssq; }
    __syncthreads();
    if (tid == 0) {
        const float s0 = sred[0][0] + sred[1][0];
        const float s1 = sred[0][1] + sred[1][1];
        const int bg = b * 4 + (h >> 1);
        atomicAdd(&stats[bg * 2], s0);
        atomicAdd(&stats[bg * 2 + 1], s1);
    }
#undef STAGE_ATTN
}

// ---------------------------------------------------------------------------
// Kernel 4: output GEMM with GN folded algebraically. [round-7 best:
// 3-buffer counted vmcnt, XCD swizzle, LDS-staged epilogue]
// ---------------------------------------------------------------------------
__global__ __launch_bounds__(256) void out_gemm_kernel(
    const bf16* __restrict__ o, const bf16* __restrict__ owg,
    const float* __restrict__ S0, const float* __restrict__ stats,
    const float* __restrict__ ob, float* __restrict__ y)
{
    __shared__ __align__(16) bf16 sh[24576];   // 48 KB: 3x(A|B); reused as Tf

    const int tid = threadIdx.x;
    const int wave = tid >> 6, lane = tid & 63;
    const int l15 = lane & 15, quad = lane >> 4;

    // XCD swizzle: 512 blocks = 8 XCDs x 64.
    const int swzb = (blockIdx.x & 7) * 64 + (blockIdx.x >> 3);
    const int mb = swzb >> 3;
    const int nb = swzb & 7;
    const int b = mb >> 5;

    const float N = 128.f * 2048.f;
    float mu[4], rs[4];
#pragma unroll
    for (int g = 0; g < 4; ++g) {
        const float m = stats[(b * 4 + g) * 2] / N;
        const float var = stats[(b * 4 + g) * 2 + 1] / N - m * m;
        mu[g] = m;
        rs[g] = rsqrtf(var + EPS);
    }

    const int srow = lane >> 3;                   // 0..7
    const int scol = 8 * ((lane & 7) ^ srow);     // swizzled source col
    const bf16* ag = o + (size_t)(mb * 64 + srow) * 512 + scol;
    const bf16* bg = owg + (size_t)(nb * 64 + srow) * 512 + scol;

#define STAGE_OUT(abuf, bbuf, s) do {                                          \
    const int k0_ = (s) * 64;                                                  \
    _Pragma("unroll")                                                          \
    for (int c_ = 0; c_ < 2; ++c_) {                                           \
        const int chunk_ = wave * 2 + c_;                                      \
        gload_lds16(ag + (size_t)(chunk_ * 8) * 512 + k0_, (abuf) + chunk_ * 512); \
        gload_lds16(bg + (size_t)(chunk_ * 8) * 512 + k0_, (bbuf) + chunk_ * 512); \
    }                                                                          \
} while (0)

    f32x4 acc[4], tot[4];
#pragma unroll
    for (int i = 0; i < 4; ++i) {
        acc[i] = (f32x4){0.f, 0.f, 0.f, 0.f};
        tot[i] = (f32x4){0.f, 0.f, 0.f, 0.f};
    }
    float s1g[4];
    float s1p = 0.f;
#pragma unroll
    for (int g = 0; g < 4; ++g) s1g[g] = 0.f;

    // Prologue: stage kk=0 and kk=1 (8 loads in flight per wave).
    STAGE_OUT(sh, sh + 12288, 0);
    STAGE_OUT(sh + 4096, sh + 12288 + 4096, 1);

    const int ka = 8 * (quad ^ (l15 & 7));

    int cur = 0;
    for (int kk = 0; kk < 8; ++kk) {
        if (kk < 7) {
            asm volatile("s_waitcnt vmcnt(4) lgkmcnt(0)\ns_barrier" ::: "memory");
        } else {
            asm volatile("s_waitcnt vmcnt(0) lgkmcnt(0)\ns_barrier" ::: "memory");
        }
        __builtin_amdgcn_sched_barrier(0);

        const bf16* Ac = sh + cur * 4096;
        const bf16* Bc = sh + 12288 + cur * 4096;
        const int n2 = (cur == 0) ? 2 : cur - 1;      // (cur+2)%3
        if (kk < 6) STAGE_OUT(sh + n2 * 4096, sh + 12288 + n2 * 4096, kk + 2);

        bf16x8 al[4], ah[4];
#pragma unroll
        for (int i = 0; i < 4; ++i) {
            const bf16* p = Ac + (i * 16 + l15) * 64;
            al[i] = *(const bf16x8*)(p + ka);
            ah[i] = *(const bf16x8*)(p + (ka ^ 32));
        }
        const bf16* pb = Bc + (wave * 16 + l15) * 64;
        const bf16x8 bl = *(const bf16x8*)(pb + ka);
        const bf16x8 bh = *(const bf16x8*)(pb + (ka ^ 32));

#pragma unroll
        for (int i = 0; i < 4; ++i) {
            acc[i] = MFMA16(al[i], bl, acc[i]);
            acc[i] = MFMA16(ah[i], bh, acc[i]);
        }

#pragma unroll
        for (int j = 0; j < 8; ++j) s1p += (float)bl[j] + (float)bh[j];

        if (kk & 1) {
            const int g = kk >> 1;
#pragma unroll
            for (int i = 0; i < 4; ++i) {
#pragma unroll
                for (int r = 0; r < 4; ++r) tot[i][r] += rs[g] * acc[i][r];
                acc[i] = (f32x4){0.f, 0.f, 0.f, 0.f};
            }
            float sg = s1p + __shfl_xor(s1p, 16, 64);
            sg += __shfl_xor(sg, 32, 64);
            s1g[g] = sg;
            s1p = 0.f;
        }

        cur = (cur == 2) ? 0 : cur + 1;
    }
    __syncthreads();      // all waves past the loop; sh reusable as Tf

    const int ncol = nb * 64 + wave * 16 + l15;
    float bias = S0[ncol] + ob[ncol];
#pragma unroll
    for (int g = 0; g < 4; ++g) bias -= mu[g] * rs[g] * s1g[g];

    // LDS-staged epilogue: Tf[m][n ^ (quad(m)<<4)] f32, then coalesced rows.
    float* const Tf = (float*)sh;                 // 64x64 f32 = 16 KB
    const int nl = wave * 16 + l15;
#pragma unroll
    for (int i = 0; i < 4; ++i) {
        const int mbase = i * 16 + quad * 4;
#pragma unroll
        for (int r = 0; r < 4; ++r)
            Tf[(mbase + r) * 64 + (nl ^ (quad << 4))] = tot[i][r] + bias;
    }
    __syncthreads();

#pragma unroll
    for (int ps = 0; ps < 4; ++ps) {
        const int idx = (ps * 256 + tid) * 4;     // 0..4095
        const int m = idx >> 6, n4 = idx & 63;
        const f32x4 v = *(const f32x4*)(Tf + m * 64 + (n4 ^ (((m >> 2) & 3) << 4)));
        *(f32x4*)(y + (size_t)(mb * 64 + m) * 512 + nb * 64 + n4) = v;
    }
#undef STAGE_OUT
}

// ---------------------------------------------------------------------------
extern "C" void kernel_launch(void* const* d_in, const int* in_sizes, int n_in,
                              void* d_out, int out_size, void* d_ws, size_t ws_size,
                              hipStream_t stream)
{
    const float* x   = (const float*)d_in[0];
    const float* K1w = (const float*)d_in[1];
    const float* K1b = (const float*)d_in[2];
    const float* Q1w = (const float*)d_in[3];
    const float* K2w = (const float*)d_in[4];
    const float* K2b = (const float*)d_in[5];
    const float* Q2w = (const float*)d_in[6];
    const float* Vw  = (const float*)d_in[7];
    const float* lq1 = (const float*)d_in[8];
    const float* lk1 = (const float*)d_in[9];
    const float* lq2 = (const float*)d_in[10];
    const float* lk2 = (const float*)d_in[11];
    const float* gnw = (const float*)d_in[12];
    const float* gnb = (const float*)d_in[13];
    const float* Ow  = (const float*)d_in[14];
    const float* Ob  = (const float*)d_in[15];

    const size_t SZ = (size_t)2 * 8 * 2048 * 64;   // 2M elements per tensor
    bf16* q1 = (bf16*)d_ws;
    bf16* k1 = q1 + SZ;
    bf16* q2 = k1 + SZ;
    bf16* k2 = q2 + SZ;
    bf16* vt = k2 + SZ;
    bf16* o  = vt + SZ;                 // attn output; slot shared with xb
    bf16* xb = o;                       // x bf16 (2M elems) — dead before attn writes o
    bf16* wb = o + SZ;                  // 2560x512 bf16 (2.6 MB)
    bf16* owg = wb + (size_t)2560 * 512;
    float* S0 = (float*)(owg + 512 * 512);
    float* stats = S0 + 512;

    prep_kernel<<<1696, 256, 0, stream>>>(x, Q1w, K1w, Q2w, K2w, Vw,
                                          Ow, gnw, gnb, xb, wb, owg, S0, stats);
    proj_kernel<<<640, 256, 0, stream>>>(xb, wb, K1b, K2b,
                                         q1, k1, q2, k2, vt);
    attn_kernel<<<512, 512, 0, stream>>>(q1, k1, q2, k2, vt,
                                         lq1, lk1, lq2, lk2, o, stats);
    out_gemm_kernel<<<512, 256, 0, stream>>>(o, owg, S0, stats, Ob,
                                             (float*)d_out);
}

// Round 11
// 169.530 us; speedup vs baseline: 1.6111x; 1.0008x over previous
//
#include <hip/hip_runtime.h>
#include <hip/hip_bf16.h>

typedef __bf16 bf16;
typedef __attribute__((ext_vector_type(4))) __bf16 bf16x4;
typedef __attribute__((ext_vector_type(8))) __bf16 bf16x8;
typedef __attribute__((ext_vector_type(4))) float f32x4;

#define MFMA16(a, b, c) __builtin_amdgcn_mfma_f32_16x16x32_bf16((a), (b), (c), 0, 0, 0)

// B=2, S=2048, D=512, H=8, hd=64, G=4. All I/O float32; bf16 MFMA compute.
static constexpr float EPS = 1e-5f;
static constexpr float LAMBDA_INIT = 0.2f;
static constexpr float LOG2E = 1.44269504088896340736f;

// Load 8 consecutive f32 (32B, 16B-aligned) and convert to bf16x8.
__device__ __forceinline__ bf16x8 cvt8(const float* p) {
    const f32x4 a = *(const f32x4*)p;
    const f32x4 b = *(const f32x4*)(p + 4);
    bf16x8 r;
    r[0] = (bf16)a[0]; r[1] = (bf16)a[1]; r[2] = (bf16)a[2]; r[3] = (bf16)a[3];
    r[4] = (bf16)b[0]; r[5] = (bf16)b[1]; r[6] = (bf16)b[2]; r[7] = (bf16)b[3];
    return r;
}

// Async 16B global -> LDS (lane i lands at lds_base + i*16; base wave-uniform).
__device__ __forceinline__ void gload_lds16(const void* g, void* l) {
    __builtin_amdgcn_global_load_lds(
        (const __attribute__((address_space(1))) unsigned int*)g,
        (__attribute__((address_space(3))) unsigned int*)l,
        16, 0, 0);
}

// ---------------------------------------------------------------------------
// Kernel 1: combined cvt + prep (wave-parallel GN section). [unchanged r10]
// ---------------------------------------------------------------------------
__global__ __launch_bounds__(256) void prep_kernel(
    const float* __restrict__ x,
    const float* __restrict__ q1w, const float* __restrict__ k1w,
    const float* __restrict__ q2w, const float* __restrict__ k2w,
    const float* __restrict__ vw,
    const float* __restrict__ ow, const float* __restrict__ gnw,
    const float* __restrict__ gnb,
    bf16* __restrict__ xb, bf16* __restrict__ wb,
    bf16* __restrict__ owg, float* __restrict__ S0, float* __restrict__ stats)
{
    const int tid = threadIdx.x;
    if (blockIdx.x < 1664) {
        const size_t base = ((size_t)blockIdx.x * 256 + tid) * 8;
        if (base < 2097152) {                    // x: 2*2048*512
            *(bf16x8*)(xb + base) = cvt8(x + base);
        } else {
            const size_t wbase = base - 2097152; // 0..1310720 (5 x 262144)
            const int wsel = (int)(wbase >> 18);
            const size_t off = wbase & 262143;
            const float* W = (wsel == 0) ? q1w : (wsel == 1) ? k1w :
                             (wsel == 2) ? q2w : (wsel == 3) ? k2w : vw;
            *(bf16x8*)(wb + wbase) = cvt8(W + off);
        }
        return;
    }

    const int pb = blockIdx.x - 1664;            // 0..31
    if (pb == 0 && tid < 16) stats[tid] = 0.f;

    const int wave = tid >> 6, lane = tid & 63;
    const int c0 = lane * 8;                     // 8 cols per lane
    const f32x4 gw0 = *(const f32x4*)(gnw + c0);
    const f32x4 gw1 = *(const f32x4*)(gnw + c0 + 4);
    const f32x4 gb0 = *(const f32x4*)(gnb + c0);
    const f32x4 gb1 = *(const f32x4*)(gnb + c0 + 4);

#pragma unroll
    for (int rr = 0; rr < 4; ++rr) {
        const int n = pb * 16 + wave * 4 + rr;
        const float* p = ow + (size_t)n * 512 + c0;
        const f32x4 w0 = *(const f32x4*)p;
        const f32x4 w1 = *(const f32x4*)(p + 4);
        bf16x8 og;
        float s = 0.f;
#pragma unroll
        for (int j = 0; j < 4; ++j) {
            og[j]     = (bf16)(w0[j] * gw0[j]);
            og[4 + j] = (bf16)(w1[j] * gw1[j]);
            s += gb0[j] * w0[j] + gb1[j] * w1[j];
        }
        *(bf16x8*)(owg + (size_t)n * 512 + c0) = og;
#pragma unroll
        for (int off = 1; off < 64; off <<= 1) s += __shfl_xor(s, off, 64);
        if (lane == 0) S0[n] = s;
    }
}

// ---------------------------------------------------------------------------
// Kernel 2: fused QKV projection GEMM. [unchanged r10 best]
// ---------------------------------------------------------------------------
__global__ __launch_bounds__(256) void proj_kernel(
    const bf16* __restrict__ xb, const bf16* __restrict__ wb,
    const float* __restrict__ k1b, const float* __restrict__ k2b,
    bf16* __restrict__ q1o, bf16* __restrict__ k1o,
    bf16* __restrict__ q2o, bf16* __restrict__ k2o,
    bf16* __restrict__ vto)
{
    __shared__ __align__(16) bf16 sh[32768];   // 64 KB: As[2]|Bs[2]; reused as T
    bf16* const As0 = sh;
    bf16* const As1 = sh + 8192;
    bf16* const Bs0 = sh + 16384;
    bf16* const Bs1 = sh + 24576;

    const int tid = threadIdx.x;
    const int wave = tid >> 6, lane = tid & 63;
    const int l15 = lane & 15, quad = lane >> 4;
    const int wm = wave >> 1, wn = wave & 1;

    // XCD swizzle: 640 blocks = 8 XCDs x 80.
    const int swzb = (blockIdx.x & 7) * 80 + (blockIdx.x >> 3);
    const int mb = swzb / 20;
    const int nb = swzb % 20;
    const int wsel = nb >> 2;
    const int nrow0 = (nb & 3) * 128;

    const int srow = lane >> 3;                   // 0..7 row within chunk
    const int scol = 8 * ((lane & 7) ^ srow);     // swizzled source col
    const bf16* ag = xb + (size_t)(mb * 128 + srow) * 512 + scol;
    const bf16* bg = wb + (size_t)(wsel * 512 + nrow0 + srow) * 512 + scol;

    f32x4 acc[4][4];
#pragma unroll
    for (int i = 0; i < 4; ++i)
#pragma unroll
        for (int j = 0; j < 4; ++j)
            acc[i][j] = (f32x4){0.f, 0.f, 0.f, 0.f};

#define STAGE_PROJ(abuf, bbuf, s) do {                                         \
    const int k0_ = (s) * 64;                                                  \
    _Pragma("unroll")                                                          \
    for (int c_ = 0; c_ < 4; ++c_) {                                           \
        const int chunk_ = wave * 4 + c_;                                      \
        gload_lds16(ag + (size_t)(chunk_ * 8) * 512 + k0_, (abuf) + chunk_ * 512); \
        gload_lds16(bg + (size_t)(chunk_ * 8) * 512 + k0_, (bbuf) + chunk_ * 512); \
    }                                                                          \
} while (0)

    STAGE_PROJ(As0, Bs0, 0);
    __syncthreads();

    const int ka = 8 * (quad ^ (l15 & 7));        // k 0..31 chunk (swizzled)

    for (int s = 0; s < 8; ++s) {
        const bf16* Ac = (s & 1) ? As1 : As0;
        const bf16* Bc = (s & 1) ? Bs1 : Bs0;
        if (s < 7) {
            if (s & 1) STAGE_PROJ(As0, Bs0, s + 1);
            else       STAGE_PROJ(As1, Bs1, s + 1);
        }

        bf16x8 al[4], ah[4], bl[4], bh_[4];
#pragma unroll
        for (int i = 0; i < 4; ++i) {
            const bf16* p = Ac + (wm * 64 + i * 16 + l15) * 64;
            al[i] = *(const bf16x8*)(p + ka);
            ah[i] = *(const bf16x8*)(p + (ka ^ 32));
        }
#pragma unroll
        for (int j = 0; j < 4; ++j) {
            const bf16* p = Bc + (wn * 64 + j * 16 + l15) * 64;
            bl[j]  = *(const bf16x8*)(p + ka);
            bh_[j] = *(const bf16x8*)(p + (ka ^ 32));
        }

#pragma unroll
        for (int i = 0; i < 4; ++i)
#pragma unroll
            for (int j = 0; j < 4; ++j) {
                acc[i][j] = MFMA16(al[i], bl[j], acc[i][j]);
                acc[i][j] = MFMA16(ah[i], bh_[j], acc[i][j]);
            }

        __syncthreads();
    }

    const int bidx = mb >> 4;
    const int sbase = (mb & 15) * 128;
    const float scale = (wsel == 0 || wsel == 2) ? 0.125f * LOG2E : 1.0f;

    if (wsel != 4) {
        // ---- q/k epilogue: T[m][n ^ (quad(m)<<4)], then linear head chunks.
        bf16* const T = sh;                       // 128x128 bf16 = 32 KB
        const int swzq = quad << 4;               // (m>>2)&3 == quad here
#pragma unroll
        for (int j = 0; j < 4; ++j) {
            const int nl = wn * 64 + j * 16 + l15;
            const int ncol = nrow0 + nl;
            float bias = 0.f;
            if (wsel == 1) bias = k1b[ncol];
            if (wsel == 3) bias = k2b[ncol];
            const int nswz = nl ^ swzq;
#pragma unroll
            for (int i = 0; i < 4; ++i) {
                const int mbase = wm * 64 + i * 16 + quad * 4;
#pragma unroll
                for (int r = 0; r < 4; ++r)
                    T[(mbase + r) * 128 + nswz] = (bf16)(acc[i][j][r] * scale + bias);
            }
        }
        __syncthreads();

        bf16* const dst = (wsel == 0) ? q1o : (wsel == 1) ? k1o :
                          (wsel == 2) ? q2o : k2o;
#pragma unroll
        for (int hsel = 0; hsel < 2; ++hsel) {
            const int h = (nrow0 >> 6) + hsel;
            bf16* db = dst + ((size_t)(bidx * 8 + h) * 2048 + sbase) * 64;
#pragma unroll
            for (int ps = 0; ps < 4; ++ps) {
                const int idx = (ps * 256 + tid) * 8;     // 0..8191
                const int m = idx >> 6, hd = idx & 63;
                const bf16x8 v = *(const bf16x8*)(
                    T + m * 128 + ((hsel * 64 + hd) ^ (((m >> 2) & 3) << 4)));
                *(bf16x8*)(db + idx) = v;
            }
        }
    } else {
        // ---- V epilogue: Tt[n][sp] (pitch 132, 4-elem XOR swizzle), with the
        // period-32 s-permutation folded into the column index; then 256B rows.
        bf16* const Tt = sh;                      // 128x132 bf16 = 33 KB
#pragma unroll
        for (int j = 0; j < 4; ++j) {
            const int nl = wn * 64 + j * 16 + l15;
            const int hd = (nrow0 + nl) & 63;
            const int xh = (hd >> 1) & 3;
            const int swz = (nl & 7) << 2;
#pragma unroll
            for (int i = 0; i < 4; ++i) {
                const int colb = (wm * 64 + (i >> 1) * 32 + ((quad ^ xh) << 3)
                                  + ((i & 1) << 2)) ^ swz;
                bf16x4 pk;
#pragma unroll
                for (int r = 0; r < 4; ++r) pk[r] = (bf16)acc[i][j][r];
                *(bf16x4*)(Tt + nl * 132 + colb) = pk;
            }
        }
        __syncthreads();

#pragma unroll
        for (int ps = 0; ps < 8; ++ps) {
            const int rown = ps * 16 + (tid >> 4);        // n_local 0..127
            const int seg = tid & 15;                     // 8-elem segment
            const int swz = (rown & 7) << 2;
            const bf16x4 lo = *(const bf16x4*)(Tt + rown * 132 + ((seg * 8) ^ swz));
            const bf16x4 hi = *(const bf16x4*)(Tt + rown * 132 + ((seg * 8 + 4) ^ swz));
            const int ncol = nrow0 + rown;
            const int h = ncol >> 6, hd = ncol & 63;
            bf16x8 v;
            v[0] = lo[0]; v[1] = lo[1]; v[2] = lo[2]; v[3] = lo[3];
            v[4] = hi[0]; v[5] = hi[1]; v[6] = hi[2]; v[7] = hi[3];
            *(bf16x8*)(vto + ((size_t)(bidx * 8 + h) * 64 + hd) * 2048
                       + sbase + seg * 8) = v;
        }
    }
#undef STAGE_PROJ
}

// ---------------------------------------------------------------------------
// Kernel 3: dual-stream flash attention + fused GroupNorm partial stats.
// This round: DEFERRED-PV via 3 LDS buffers (spill-free form of r6's idea).
// Per iter: read K(it) + V(it-1) (8 ds_reads, same count), run QK(it) MFMAs,
// then PV(it-1) MFMAs (independent of QK — fills QK's latency window), then
// exp(it) -> carried P (only 2 bf16x8 carried; V re-read from LDS, slot
// provably live: stage at iter t writes slot (t+1)%3 = (t-2)%3). Plain
// __syncthreads (no asm pinning — r6's spill trigger avoided). LDS 72 KB,
// still 2 blocks/CU (grid-limited).
// ---------------------------------------------------------------------------
__global__ __launch_bounds__(512, 4) void attn_kernel(
    const bf16* __restrict__ q1, const bf16* __restrict__ k1,
    const bf16* __restrict__ q2, const bf16* __restrict__ k2,
    const bf16* __restrict__ vt,
    const float* __restrict__ lq1, const float* __restrict__ lk1,
    const float* __restrict__ lq2, const float* __restrict__ lk2,
    bf16* __restrict__ o, float* __restrict__ stats)
{
    __shared__ __align__(16) bf16 smem[3][12288];   // 72 KB: 3 x (K1 | K2 | V)
    __shared__ float lbuf[8][2][16];
    __shared__ float sred[2][2];

    const int tid = threadIdx.x;
    const int wave = tid >> 6;
    const int lane = tid & 63;
    const int l15 = lane & 15, quad = lane >> 4;
    const int kg = wave >> 2;         // key group (0: keys 0..1023, 1: 1024..)
    const int w4 = wave & 3;
    const int qp = w4 & 1;            // q-pair: tiles {2qp, 2qp+1}
    const int st = w4 >> 1;           // stream: 0 -> (q1,k1), 1 -> (q2,k2)

    // XCD-aware remap (512 = 8 XCDs x 64, bijective).
    const int rid = (blockIdx.x & 7) * 64 + (blockIdx.x >> 3);
    const int bh = rid >> 5;
    const int qt = rid & 31;
    const int b = bh >> 3, h = bh & 7;

    const bf16* k1t = k1 + (size_t)bh * 2048 * 64;
    const bf16* k2t = k2 + (size_t)bh * 2048 * 64;
    const bf16* vtt = vt + (size_t)bh * 64 * 2048;

    // Q fragments for this wave's stream, 2 q-tiles (rows qp*32 .. qp*32+31).
    const bf16* qs = st ? q2 : q1;
    const int qrowA = qt * 64 + qp * 32 + l15;
    const bf16* qpA = qs + ((size_t)bh * 2048 + qrowA) * 64 + quad * 8;
    const bf16x8 qA0 = *(const bf16x8*)(qpA);
    const bf16x8 qA1 = *(const bf16x8*)(qpA + 32);
    const bf16x8 qB0 = *(const bf16x8*)(qpA + 16 * 64);
    const bf16x8 qB1 = *(const bf16x8*)(qpA + 16 * 64 + 32);

    // Staging: contents independent of wave->work mapping.
    const int sw = wave & 3;
    const int skey0 = (wave < 4) ? 0 : 1024;
    const size_t ksrc0 = (size_t)(skey0 + sw * 8 + (lane >> 3)) * 64
                       + 8 * ((lane & 7) ^ (lane >> 3));
    const size_t vsrc0 = (size_t)(sw * 16 + (lane >> 2)) * 2048 + skey0 + (lane & 3) * 8;

#define STAGE_ATTN(buf, itv) do {                                   \
    const size_t koff_ = ksrc0 + (size_t)(itv) * 32 * 64;           \
    gload_lds16(k1t + koff_, (buf) + wave * 512);                   \
    gload_lds16(k2t + koff_, (buf) + 4096 + wave * 512);            \
    gload_lds16(vtt + vsrc0 + (itv) * 32, (buf) + 8192 + wave * 512); \
} while (0)

    const int koffa = 8 * (quad ^ (l15 & 7));
    const int koffb = 8 * ((quad + 4) ^ (l15 & 7));
    const int vsw = 8 * (quad ^ ((l15 >> 1) & 3));   // matches proj's xh perm

    f32x4 OA[4], OB[4];
    float lA = 0.f, lB = 0.f;
#pragma unroll
    for (int t = 0; t < 4; ++t) {
        OA[t] = (f32x4){0.f, 0.f, 0.f, 0.f};
        OB[t] = (f32x4){0.f, 0.f, 0.f, 0.f};
    }

    bf16x8 pbA, pbB;                   // carried P (deferred PV), 8 VGPR

    STAGE_ATTN(smem[0], 0);
    __syncthreads();

    int cur = 0;
    for (int it = 0; it < 32; ++it) {
        const int nxt = (cur == 2) ? 0 : cur + 1;
        const int prv = (cur == 0) ? 2 : cur - 1;   // slot of tile it-1
        if (it < 31) STAGE_ATTN(smem[nxt], it + 1); // writes slot (it-2)%3: safe

        // K(it) reads (this wave's stream + kg only).
        const bf16* kr = smem[cur] + st * 4096 + kg * 2048;
        const bf16x8 kt0a = *(const bf16x8*)(kr + l15 * 64 + koffa);
        const bf16x8 kt0b = *(const bf16x8*)(kr + l15 * 64 + koffb);
        const bf16x8 kt1a = *(const bf16x8*)(kr + (16 + l15) * 64 + koffa);
        const bf16x8 kt1b = *(const bf16x8*)(kr + (16 + l15) * 64 + koffb);

        // QK(it) — the head of the dependency chain.
        const f32x4 z = (f32x4){0.f, 0.f, 0.f, 0.f};
        __builtin_amdgcn_s_setprio(1);
        f32x4 sA0 = MFMA16(kt0a, qA0, z);  sA0 = MFMA16(kt0b, qA1, sA0);
        f32x4 sA1 = MFMA16(kt1a, qA0, z);  sA1 = MFMA16(kt1b, qA1, sA1);
        f32x4 sB0 = MFMA16(kt0a, qB0, z);  sB0 = MFMA16(kt0b, qB1, sB0);
        f32x4 sB1 = MFMA16(kt1a, qB0, z);  sB1 = MFMA16(kt1b, qB1, sB1);
        __builtin_amdgcn_s_setprio(0);

        // PV(it-1): V from LDS slot prv, P carried — independent of QK(it),
        // executes inside QK's latency/exp window.
        if (it > 0) {
            const bf16* vp = smem[prv] + 8192 + kg * 2048;
            const bf16x8 v0 = *(const bf16x8*)(vp + l15 * 32 + vsw);
            const bf16x8 v1 = *(const bf16x8*)(vp + (16 + l15) * 32 + vsw);
            const bf16x8 v2 = *(const bf16x8*)(vp + (32 + l15) * 32 + vsw);
            const bf16x8 v3 = *(const bf16x8*)(vp + (48 + l15) * 32 + vsw);
            __builtin_amdgcn_s_setprio(1);
            OA[0] = MFMA16(v0, pbA, OA[0]);
            OA[1] = MFMA16(v1, pbA, OA[1]);
            OA[2] = MFMA16(v2, pbA, OA[2]);
            OA[3] = MFMA16(v3, pbA, OA[3]);
            OB[0] = MFMA16(v0, pbB, OB[0]);
            OB[1] = MFMA16(v1, pbB, OB[1]);
            OB[2] = MFMA16(v2, pbB, OB[2]);
            OB[3] = MFMA16(v3, pbB, OB[3]);
            __builtin_amdgcn_s_setprio(0);
        }

        // exp(it) -> carried P for next iteration's PV.
        bf16x8 bA, bB;
#pragma unroll
        for (int r = 0; r < 4; ++r) {
            float e;
            e = __builtin_amdgcn_exp2f(sA0[r]); lA += e; bA[r]     = (bf16)e;
            e = __builtin_amdgcn_exp2f(sA1[r]); lA += e; bA[4 + r] = (bf16)e;
            e = __builtin_amdgcn_exp2f(sB0[r]); lB += e; bB[r]     = (bf16)e;
            e = __builtin_amdgcn_exp2f(sB1[r]); lB += e; bB[4 + r] = (bf16)e;
        }
        pbA = bA;  pbB = bB;

        __syncthreads();
        cur = nxt;
    }

    // Final deferred PV: V(31) lives in slot (cur+2)%3, untouched since.
    {
        const int prv = (cur == 0) ? 2 : cur - 1;
        const bf16* vp = smem[prv] + 8192 + kg * 2048;
        const bf16x8 v0 = *(const bf16x8*)(vp + l15 * 32 + vsw);
        const bf16x8 v1 = *(const bf16x8*)(vp + (16 + l15) * 32 + vsw);
        const bf16x8 v2 = *(const bf16x8*)(vp + (32 + l15) * 32 + vsw);
        const bf16x8 v3 = *(const bf16x8*)(vp + (48 + l15) * 32 + vsw);
        OA[0] = MFMA16(v0, pbA, OA[0]);
        OA[1] = MFMA16(v1, pbA, OA[1]);
        OA[2] = MFMA16(v2, pbA, OA[2]);
        OA[3] = MFMA16(v3, pbA, OA[3]);
        OB[0] = MFMA16(v0, pbB, OB[0]);
        OB[1] = MFMA16(v1, pbB, OB[1]);
        OB[2] = MFMA16(v2, pbB, OB[2]);
        OB[3] = MFMA16(v3, pbB, OB[3]);
    }

    // Quad-replica reduce of l, publish per-wave partial l.
    lA += __shfl_xor(lA, 16, 64);  lA += __shfl_xor(lA, 32, 64);
    lB += __shfl_xor(lB, 16, 64);  lB += __shfl_xor(lB, 32, 64);
    if (lane < 16) {
        lbuf[wave][0][lane] = lA;
        lbuf[wave][1][lane] = lB;
    }
    __syncthreads();   // also drains final-PV ds_reads before smem reuse

    // Stage 1: kg-combine. kg=1 waves export OA,OB; kg=0 waves accumulate.
    f32x4* rb = (f32x4*)smem;
    if (kg == 1) {
        f32x4* dst = rb + w4 * 512;
#pragma unroll
        for (int t = 0; t < 4; ++t) {
            dst[t * 64 + lane]       = OA[t];
            dst[(4 + t) * 64 + lane] = OB[t];
        }
    }
    __syncthreads();
    if (kg == 0) {
        const f32x4* src = rb + w4 * 512;
#pragma unroll
        for (int t = 0; t < 4; ++t) {
            OA[t] += src[t * 64 + lane];
            OB[t] += src[(4 + t) * 64 + lane];
        }
    }
    __syncthreads();

    // Stage 2: stream-combine. kg=0,st=1 waves (2,3) export full-key O2.
    if (kg == 0 && st == 1) {
        f32x4* dst = rb + qp * 512;
#pragma unroll
        for (int t = 0; t < 4; ++t) {
            dst[t * 64 + lane]       = OA[t];
            dst[(4 + t) * 64 + lane] = OB[t];
        }
    }
    __syncthreads();

    float ssum = 0.f, ssq = 0.f;
    if (kg == 0 && st == 0) {                     // waves 0,1: final combine
        const f32x4* src = rb + qp * 512;         // stream-2 full-key O
        const float L1A = lA + lbuf[4 + qp][0][l15];
        const float L1B = lB + lbuf[4 + qp][1][l15];
        const float L2A = lbuf[2 + qp][0][l15] + lbuf[6 + qp][0][l15];
        const float L2B = lbuf[2 + qp][1][l15] + lbuf[6 + qp][1][l15];
        const float lam = __expf(lq1[h] * lk1[h]) - __expf(lq2[h] * lk2[h]) + LAMBDA_INIT;
        const float i1A = 1.f / L1A, i2A = lam / L2A;
        const float i1B = 1.f / L1B, i2B = lam / L2B;
        const size_t rowA = (size_t)(b * 2048 + qt * 64 + qp * 32 + l15) * 512 + h * 64;
        const size_t rowB = rowA + 16 * 512;
#pragma unroll
        for (int t = 0; t < 4; ++t) {
            const f32x4 o2A = src[t * 64 + lane];
            const f32x4 o2B = src[(4 + t) * 64 + lane];
#pragma unroll
            for (int r = 0; r < 4; ++r) {
                const float vA = OA[t][r] * i1A - o2A[r] * i2A;
                const float vB = OB[t][r] * i1B - o2B[r] * i2B;
                ssum += vA + vB;
                ssq += vA * vA + vB * vB;
                o[rowA + t * 16 + quad * 4 + r] = (bf16)vA;
                o[rowB + t * 16 + quad * 4 + r] = (bf16)vB;
            }
        }
    }
#pragma unroll
    for (int off = 1; off < 64; off <<= 1) {
        ssum += __shfl_xor(ssum, off, 64);
        ssq += __shfl_xor(ssq, off, 64);
    }
    if (kg == 0 && st == 0 && lane == 0) { sred[qp][0] = ssum; sred[qp][1] = ssq; }
    __syncthreads();
    if (tid == 0) {
        const float s0 = sred[0][0] + sred[1][0];
        const float s1 = sred[0][1] + sred[1][1];
        const int bg = b * 4 + (h >> 1);
        atomicAdd(&stats[bg * 2], s0);
        atomicAdd(&stats[bg * 2 + 1], s1);
    }
#undef STAGE_ATTN
}

// ---------------------------------------------------------------------------
// Kernel 4: output GEMM with GN folded algebraically. [unchanged r10 best]
// ---------------------------------------------------------------------------
__global__ __launch_bounds__(256) void out_gemm_kernel(
    const bf16* __restrict__ o, const bf16* __restrict__ owg,
    const float* __restrict__ S0, const float* __restrict__ stats,
    const float* __restrict__ ob, float* __restrict__ y)
{
    __shared__ __align__(16) bf16 sh[24576];   // 48 KB: 3x(A|B); reused as Tf

    const int tid = threadIdx.x;
    const int wave = tid >> 6, lane = tid & 63;
    const int l15 = lane & 15, quad = lane >> 4;

    // XCD swizzle: 512 blocks = 8 XCDs x 64.
    const int swzb = (blockIdx.x & 7) * 64 + (blockIdx.x >> 3);
    const int mb = swzb >> 3;
    const int nb = swzb & 7;
    const int b = mb >> 5;

    const float N = 128.f * 2048.f;
    float mu[4], rs[4];
#pragma unroll
    for (int g = 0; g < 4; ++g) {
        const float m = stats[(b * 4 + g) * 2] / N;
        const float var = stats[(b * 4 + g) * 2 + 1] / N - m * m;
        mu[g] = m;
        rs[g] = rsqrtf(var + EPS);
    }

    const int srow = lane >> 3;                   // 0..7
    const int scol = 8 * ((lane & 7) ^ srow);     // swizzled source col
    const bf16* ag = o + (size_t)(mb * 64 + srow) * 512 + scol;
    const bf16* bg = owg + (size_t)(nb * 64 + srow) * 512 + scol;

#define STAGE_OUT(abuf, bbuf, s) do {                                          \
    const int k0_ = (s) * 64;                                                  \
    _Pragma("unroll")                                                          \
    for (int c_ = 0; c_ < 2; ++c_) {                                           \
        const int chunk_ = wave * 2 + c_;                                      \
        gload_lds16(ag + (size_t)(chunk_ * 8) * 512 + k0_, (abuf) + chunk_ * 512); \
        gload_lds16(bg + (size_t)(chunk_ * 8) * 512 + k0_, (bbuf) + chunk_ * 512); \
    }                                                                          \
} while (0)

    f32x4 acc[4], tot[4];
#pragma unroll
    for (int i = 0; i < 4; ++i) {
        acc[i] = (f32x4){0.f, 0.f, 0.f, 0.f};
        tot[i] = (f32x4){0.f, 0.f, 0.f, 0.f};
    }
    float s1g[4];
    float s1p = 0.f;
#pragma unroll
    for (int g = 0; g < 4; ++g) s1g[g] = 0.f;

    // Prologue: stage kk=0 and kk=1 (8 loads in flight per wave).
    STAGE_OUT(sh, sh + 12288, 0);
    STAGE_OUT(sh + 4096, sh + 12288 + 4096, 1);

    const int ka = 8 * (quad ^ (l15 & 7));

    int cur = 0;
    for (int kk = 0; kk < 8; ++kk) {
        if (kk < 7) {
            asm volatile("s_waitcnt vmcnt(4) lgkmcnt(0)\ns_barrier" ::: "memory");
        } else {
            asm volatile("s_waitcnt vmcnt(0) lgkmcnt(0)\ns_barrier" ::: "memory");
        }
        __builtin_amdgcn_sched_barrier(0);

        const bf16* Ac = sh + cur * 4096;
        const bf16* Bc = sh + 12288 + cur * 4096;
        const int n2 = (cur == 0) ? 2 : cur - 1;      // (cur+2)%3
        if (kk < 6) STAGE_OUT(sh + n2 * 4096, sh + 12288 + n2 * 4096, kk + 2);

        bf16x8 al[4], ah[4];
#pragma unroll
        for (int i = 0; i < 4; ++i) {
            const bf16* p = Ac + (i * 16 + l15) * 64;
            al[i] = *(const bf16x8*)(p + ka);
            ah[i] = *(const bf16x8*)(p + (ka ^ 32));
        }
        const bf16* pb = Bc + (wave * 16 + l15) * 64;
        const bf16x8 bl = *(const bf16x8*)(pb + ka);
        const bf16x8 bh = *(const bf16x8*)(pb + (ka ^ 32));

#pragma unroll
        for (int i = 0; i < 4; ++i) {
            acc[i] = MFMA16(al[i], bl, acc[i]);
            acc[i] = MFMA16(ah[i], bh, acc[i]);
        }

#pragma unroll
        for (int j = 0; j < 8; ++j) s1p += (float)bl[j] + (float)bh[j];

        if (kk & 1) {
            const int g = kk >> 1;
#pragma unroll
            for (int i = 0; i < 4; ++i) {
#pragma unroll
                for (int r = 0; r < 4; ++r) tot[i][r] += rs[g] * acc[i][r];
                acc[i] = (f32x4){0.f, 0.f, 0.f, 0.f};
            }
            float sg = s1p + __shfl_xor(s1p, 16, 64);
            sg += __shfl_xor(sg, 32, 64);
            s1g[g] = sg;
            s1p = 0.f;
        }

        cur = (cur == 2) ? 0 : cur + 1;
    }
    __syncthreads();      // all waves past the loop; sh reusable as Tf

    const int ncol = nb * 64 + wave * 16 + l15;
    float bias = S0[ncol] + ob[ncol];
#pragma unroll
    for (int g = 0; g < 4; ++g) bias -= mu[g] * rs[g] * s1g[g];

    // LDS-staged epilogue: Tf[m][n ^ (quad(m)<<4)] f32, then coalesced rows.
    float* const Tf = (float*)sh;                 // 64x64 f32 = 16 KB
    const int nl = wave * 16 + l15;
#pragma unroll
    for (int i = 0; i < 4; ++i) {
        const int mbase = i * 16 + quad * 4;
#pragma unroll
        for (int r = 0; r < 4; ++r)
            Tf[(mbase + r) * 64 + (nl ^ (quad << 4))] = tot[i][r] + bias;
    }
    __syncthreads();

#pragma unroll
    for (int ps = 0; ps < 4; ++ps) {
        const int idx = (ps * 256 + tid) * 4;     // 0..4095
        const int m = idx >> 6, n4 = idx & 63;
        const f32x4 v = *(const f32x4*)(Tf + m * 64 + (n4 ^ (((m >> 2) & 3) << 4)));
        *(f32x4*)(y + (size_t)(mb * 64 + m) * 512 + nb * 64 + n4) = v;
    }
#undef STAGE_OUT
}

// ---------------------------------------------------------------------------
extern "C" void kernel_launch(void* const* d_in, const int* in_sizes, int n_in,
                              void* d_out, int out_size, void* d_ws, size_t ws_size,
                              hipStream_t stream)
{
    const float* x   = (const float*)d_in[0];
    const float* K1w = (const float*)d_in[1];
    const float* K1b = (const float*)d_in[2];
    const float* Q1w = (const float*)d_in[3];
    const float* K2w = (const float*)d_in[4];
    const float* K2b = (const float*)d_in[5];
    const float* Q2w = (const float*)d_in[6];
    const float* Vw  = (const float*)d_in[7];
    const float* lq1 = (const float*)d_in[8];
    const float* lk1 = (const float*)d_in[9];
    const float* lq2 = (const float*)d_in[10];
    const float* lk2 = (const float*)d_in[11];
    const float* gnw = (const float*)d_in[12];
    const float* gnb = (const float*)d_in[13];
    const float* Ow  = (const float*)d_in[14];
    const float* Ob  = (const float*)d_in[15];

    const size_t SZ = (size_t)2 * 8 * 2048 * 64;   // 2M elements per tensor
    bf16* q1 = (bf16*)d_ws;
    bf16* k1 = q1 + SZ;
    bf16* q2 = k1 + SZ;
    bf16* k2 = q2 + SZ;
    bf16* vt = k2 + SZ;
    bf16* o  = vt + SZ;                 // attn output; slot shared with xb
    bf16* xb = o;                       // x bf16 (2M elems) — dead before attn writes o
    bf16* wb = o + SZ;                  // 2560x512 bf16 (2.6 MB)
    bf16* owg = wb + (size_t)2560 * 512;
    float* S0 = (float*)(owg + 512 * 512);
    float* stats = S0 + 512;

    prep_kernel<<<1696, 256, 0, stream>>>(x, Q1w, K1w, Q2w, K2w, Vw,
                                          Ow, gnw, gnb, xb, wb, owg, S0, stats);
    proj_kernel<<<640, 256, 0, stream>>>(xb, wb, K1b, K2b,
                                         q1, k1, q2, k2, vt);
    attn_kernel<<<512, 512, 0, stream>>>(q1, k1, q2, k2, vt,
                                         lq1, lk1, lq2, lk2, o, stats);
    out_gemm_kernel<<<512, 256, 0, stream>>>(o, owg, S0, stats, Ob,
                                             (float*)d_out);
}

// Round 12
// 167.603 us; speedup vs baseline: 1.6297x; 1.0115x over previous
//
#include <hip/hip_runtime.h>
#include <hip/hip_bf16.h>

typedef __bf16 bf16;
typedef __attribute__((ext_vector_type(4))) __bf16 bf16x4;
typedef __attribute__((ext_vector_type(8))) __bf16 bf16x8;
typedef __attribute__((ext_vector_type(4))) float f32x4;

#define MFMA16(a, b, c) __builtin_amdgcn_mfma_f32_16x16x32_bf16((a), (b), (c), 0, 0, 0)

// B=2, S=2048, D=512, H=8, hd=64, G=4. All I/O float32; bf16 MFMA compute.
static constexpr float EPS = 1e-5f;
static constexpr float LAMBDA_INIT = 0.2f;
static constexpr float LOG2E = 1.44269504088896340736f;

// Load 8 consecutive f32 (32B, 16B-aligned) and convert to bf16x8.
__device__ __forceinline__ bf16x8 cvt8(const float* p) {
    const f32x4 a = *(const f32x4*)p;
    const f32x4 b = *(const f32x4*)(p + 4);
    bf16x8 r;
    r[0] = (bf16)a[0]; r[1] = (bf16)a[1]; r[2] = (bf16)a[2]; r[3] = (bf16)a[3];
    r[4] = (bf16)b[0]; r[5] = (bf16)b[1]; r[6] = (bf16)b[2]; r[7] = (bf16)b[3];
    return r;
}

// Async 16B global -> LDS (lane i lands at lds_base + i*16; base wave-uniform).
__device__ __forceinline__ void gload_lds16(const void* g, void* l) {
    __builtin_amdgcn_global_load_lds(
        (const __attribute__((address_space(1))) unsigned int*)g,
        (__attribute__((address_space(3))) unsigned int*)l,
        16, 0, 0);
}

// ---------------------------------------------------------------------------
// Kernel 1: combined cvt + prep (wave-parallel GN section).
// ---------------------------------------------------------------------------
__global__ __launch_bounds__(256) void prep_kernel(
    const float* __restrict__ x,
    const float* __restrict__ q1w, const float* __restrict__ k1w,
    const float* __restrict__ q2w, const float* __restrict__ k2w,
    const float* __restrict__ vw,
    const float* __restrict__ ow, const float* __restrict__ gnw,
    const float* __restrict__ gnb,
    bf16* __restrict__ xb, bf16* __restrict__ wb,
    bf16* __restrict__ owg, float* __restrict__ S0, float* __restrict__ stats)
{
    const int tid = threadIdx.x;
    if (blockIdx.x < 1664) {
        const size_t base = ((size_t)blockIdx.x * 256 + tid) * 8;
        if (base < 2097152) {                    // x: 2*2048*512
            *(bf16x8*)(xb + base) = cvt8(x + base);
        } else {
            const size_t wbase = base - 2097152; // 0..1310720 (5 x 262144)
            const int wsel = (int)(wbase >> 18);
            const size_t off = wbase & 262143;
            const float* W = (wsel == 0) ? q1w : (wsel == 1) ? k1w :
                             (wsel == 2) ? q2w : (wsel == 3) ? k2w : vw;
            *(bf16x8*)(wb + wbase) = cvt8(W + off);
        }
        return;
    }

    const int pb = blockIdx.x - 1664;            // 0..31
    if (pb == 0 && tid < 16) stats[tid] = 0.f;

    const int wave = tid >> 6, lane = tid & 63;
    const int c0 = lane * 8;                     // 8 cols per lane
    const f32x4 gw0 = *(const f32x4*)(gnw + c0);
    const f32x4 gw1 = *(const f32x4*)(gnw + c0 + 4);
    const f32x4 gb0 = *(const f32x4*)(gnb + c0);
    const f32x4 gb1 = *(const f32x4*)(gnb + c0 + 4);

#pragma unroll
    for (int rr = 0; rr < 4; ++rr) {
        const int n = pb * 16 + wave * 4 + rr;
        const float* p = ow + (size_t)n * 512 + c0;
        const f32x4 w0 = *(const f32x4*)p;
        const f32x4 w1 = *(const f32x4*)(p + 4);
        bf16x8 og;
        float s = 0.f;
#pragma unroll
        for (int j = 0; j < 4; ++j) {
            og[j]     = (bf16)(w0[j] * gw0[j]);
            og[4 + j] = (bf16)(w1[j] * gw1[j]);
            s += gb0[j] * w0[j] + gb1[j] * w1[j];
        }
        *(bf16x8*)(owg + (size_t)n * 512 + c0) = og;
#pragma unroll
        for (int off = 1; off < 64; off <<= 1) s += __shfl_xor(s, off, 64);
        if (lane == 0) S0[n] = s;
    }
}

// ---------------------------------------------------------------------------
// Kernel 2: fused QKV projection GEMM. [r10 best]
// ---------------------------------------------------------------------------
__global__ __launch_bounds__(256) void proj_kernel(
    const bf16* __restrict__ xb, const bf16* __restrict__ wb,
    const float* __restrict__ k1b, const float* __restrict__ k2b,
    bf16* __restrict__ q1o, bf16* __restrict__ k1o,
    bf16* __restrict__ q2o, bf16* __restrict__ k2o,
    bf16* __restrict__ vto)
{
    __shared__ __align__(16) bf16 sh[32768];   // 64 KB: As[2]|Bs[2]; reused as T
    bf16* const As0 = sh;
    bf16* const As1 = sh + 8192;
    bf16* const Bs0 = sh + 16384;
    bf16* const Bs1 = sh + 24576;

    const int tid = threadIdx.x;
    const int wave = tid >> 6, lane = tid & 63;
    const int l15 = lane & 15, quad = lane >> 4;
    const int wm = wave >> 1, wn = wave & 1;

    // XCD swizzle: 640 blocks = 8 XCDs x 80.
    const int swzb = (blockIdx.x & 7) * 80 + (blockIdx.x >> 3);
    const int mb = swzb / 20;
    const int nb = swzb % 20;
    const int wsel = nb >> 2;
    const int nrow0 = (nb & 3) * 128;

    const int srow = lane >> 3;                   // 0..7 row within chunk
    const int scol = 8 * ((lane & 7) ^ srow);     // swizzled source col
    const bf16* ag = xb + (size_t)(mb * 128 + srow) * 512 + scol;
    const bf16* bg = wb + (size_t)(wsel * 512 + nrow0 + srow) * 512 + scol;

    f32x4 acc[4][4];
#pragma unroll
    for (int i = 0; i < 4; ++i)
#pragma unroll
        for (int j = 0; j < 4; ++j)
            acc[i][j] = (f32x4){0.f, 0.f, 0.f, 0.f};

#define STAGE_PROJ(abuf, bbuf, s) do {                                         \
    const int k0_ = (s) * 64;                                                  \
    _Pragma("unroll")                                                          \
    for (int c_ = 0; c_ < 4; ++c_) {                                           \
        const int chunk_ = wave * 4 + c_;                                      \
        gload_lds16(ag + (size_t)(chunk_ * 8) * 512 + k0_, (abuf) + chunk_ * 512); \
        gload_lds16(bg + (size_t)(chunk_ * 8) * 512 + k0_, (bbuf) + chunk_ * 512); \
    }                                                                          \
} while (0)

    STAGE_PROJ(As0, Bs0, 0);
    __syncthreads();

    const int ka = 8 * (quad ^ (l15 & 7));        // k 0..31 chunk (swizzled)

    for (int s = 0; s < 8; ++s) {
        const bf16* Ac = (s & 1) ? As1 : As0;
        const bf16* Bc = (s & 1) ? Bs1 : Bs0;
        if (s < 7) {
            if (s & 1) STAGE_PROJ(As0, Bs0, s + 1);
            else       STAGE_PROJ(As1, Bs1, s + 1);
        }

        bf16x8 al[4], ah[4], bl[4], bh_[4];
#pragma unroll
        for (int i = 0; i < 4; ++i) {
            const bf16* p = Ac + (wm * 64 + i * 16 + l15) * 64;
            al[i] = *(const bf16x8*)(p + ka);
            ah[i] = *(const bf16x8*)(p + (ka ^ 32));
        }
#pragma unroll
        for (int j = 0; j < 4; ++j) {
            const bf16* p = Bc + (wn * 64 + j * 16 + l15) * 64;
            bl[j]  = *(const bf16x8*)(p + ka);
            bh_[j] = *(const bf16x8*)(p + (ka ^ 32));
        }

#pragma unroll
        for (int i = 0; i < 4; ++i)
#pragma unroll
            for (int j = 0; j < 4; ++j) {
                acc[i][j] = MFMA16(al[i], bl[j], acc[i][j]);
                acc[i][j] = MFMA16(ah[i], bh_[j], acc[i][j]);
            }

        __syncthreads();
    }

    const int bidx = mb >> 4;
    const int sbase = (mb & 15) * 128;
    const float scale = (wsel == 0 || wsel == 2) ? 0.125f * LOG2E : 1.0f;

    if (wsel != 4) {
        // ---- q/k epilogue: T[m][n ^ (quad(m)<<4)], then linear head chunks.
        bf16* const T = sh;                       // 128x128 bf16 = 32 KB
        const int swzq = quad << 4;               // (m>>2)&3 == quad here
#pragma unroll
        for (int j = 0; j < 4; ++j) {
            const int nl = wn * 64 + j * 16 + l15;
            const int ncol = nrow0 + nl;
            float bias = 0.f;
            if (wsel == 1) bias = k1b[ncol];
            if (wsel == 3) bias = k2b[ncol];
            const int nswz = nl ^ swzq;
#pragma unroll
            for (int i = 0; i < 4; ++i) {
                const int mbase = wm * 64 + i * 16 + quad * 4;
#pragma unroll
                for (int r = 0; r < 4; ++r)
                    T[(mbase + r) * 128 + nswz] = (bf16)(acc[i][j][r] * scale + bias);
            }
        }
        __syncthreads();

        bf16* const dst = (wsel == 0) ? q1o : (wsel == 1) ? k1o :
                          (wsel == 2) ? q2o : k2o;
#pragma unroll
        for (int hsel = 0; hsel < 2; ++hsel) {
            const int h = (nrow0 >> 6) + hsel;
            bf16* db = dst + ((size_t)(bidx * 8 + h) * 2048 + sbase) * 64;
#pragma unroll
            for (int ps = 0; ps < 4; ++ps) {
                const int idx = (ps * 256 + tid) * 8;     // 0..8191
                const int m = idx >> 6, hd = idx & 63;
                const bf16x8 v = *(const bf16x8*)(
                    T + m * 128 + ((hsel * 64 + hd) ^ (((m >> 2) & 3) << 4)));
                *(bf16x8*)(db + idx) = v;
            }
        }
    } else {
        // ---- V epilogue: Tt[n][sp] (pitch 132, 4-elem XOR swizzle), with the
        // period-32 s-permutation folded into the column index; then 256B rows.
        bf16* const Tt = sh;                      // 128x132 bf16 = 33 KB
#pragma unroll
        for (int j = 0; j < 4; ++j) {
            const int nl = wn * 64 + j * 16 + l15;
            const int hd = (nrow0 + nl) & 63;
            const int xh = (hd >> 1) & 3;
            const int swz = (nl & 7) << 2;
#pragma unroll
            for (int i = 0; i < 4; ++i) {
                const int colb = (wm * 64 + (i >> 1) * 32 + ((quad ^ xh) << 3)
                                  + ((i & 1) << 2)) ^ swz;
                bf16x4 pk;
#pragma unroll
                for (int r = 0; r < 4; ++r) pk[r] = (bf16)acc[i][j][r];
                *(bf16x4*)(Tt + nl * 132 + colb) = pk;
            }
        }
        __syncthreads();

#pragma unroll
        for (int ps = 0; ps < 8; ++ps) {
            const int rown = ps * 16 + (tid >> 4);        // n_local 0..127
            const int seg = tid & 15;                     // 8-elem segment
            const int swz = (rown & 7) << 2;
            const bf16x4 lo = *(const bf16x4*)(Tt + rown * 132 + ((seg * 8) ^ swz));
            const bf16x4 hi = *(const bf16x4*)(Tt + rown * 132 + ((seg * 8 + 4) ^ swz));
            const int ncol = nrow0 + rown;
            const int h = ncol >> 6, hd = ncol & 63;
            bf16x8 v;
            v[0] = lo[0]; v[1] = lo[1]; v[2] = lo[2]; v[3] = lo[3];
            v[4] = hi[0]; v[5] = hi[1]; v[6] = hi[2]; v[7] = hi[3];
            *(bf16x8*)(vto + ((size_t)(bidx * 8 + h) * 64 + hd) * 2048
                       + sbase + seg * 8) = v;
        }
    }
#undef STAGE_PROJ
}

// ---------------------------------------------------------------------------
// Kernel 3: dual-stream flash attention + fused GroupNorm partial stats.
// [r10 best — 53.5-54.4us measured: (qp,st,kg) decomposition, 2-buffer LDS
// + __syncthreads, swizzles, exp2, XCD remap. r11's 3-buffer deferred-PV
// reverted (59us, eighth falsified variant).]
// ---------------------------------------------------------------------------
__global__ __launch_bounds__(512, 4) void attn_kernel(
    const bf16* __restrict__ q1, const bf16* __restrict__ k1,
    const bf16* __restrict__ q2, const bf16* __restrict__ k2,
    const bf16* __restrict__ vt,
    const float* __restrict__ lq1, const float* __restrict__ lk1,
    const float* __restrict__ lq2, const float* __restrict__ lk2,
    bf16* __restrict__ o, float* __restrict__ stats)
{
    __shared__ __align__(16) bf16 smem[2][12288];   // 48 KB: 2 x (K1 | K2 | V)
    __shared__ float lbuf[8][2][16];
    __shared__ float sred[2][2];

    const int tid = threadIdx.x;
    const int wave = tid >> 6;
    const int lane = tid & 63;
    const int l15 = lane & 15, quad = lane >> 4;
    const int kg = wave >> 2;         // key group (0: keys 0..1023, 1: 1024..)
    const int w4 = wave & 3;
    const int qp = w4 & 1;            // q-pair: tiles {2qp, 2qp+1}
    const int st = w4 >> 1;           // stream: 0 -> (q1,k1), 1 -> (q2,k2)

    // XCD-aware remap (512 = 8 XCDs x 64, bijective).
    const int rid = (blockIdx.x & 7) * 64 + (blockIdx.x >> 3);
    const int bh = rid >> 5;
    const int qt = rid & 31;
    const int b = bh >> 3, h = bh & 7;

    const bf16* k1t = k1 + (size_t)bh * 2048 * 64;
    const bf16* k2t = k2 + (size_t)bh * 2048 * 64;
    const bf16* vtt = vt + (size_t)bh * 64 * 2048;

    // Q fragments for this wave's stream, 2 q-tiles (rows qp*32 .. qp*32+31).
    const bf16* qs = st ? q2 : q1;
    const int qrowA = qt * 64 + qp * 32 + l15;
    const bf16* qpA = qs + ((size_t)bh * 2048 + qrowA) * 64 + quad * 8;
    const bf16x8 qA0 = *(const bf16x8*)(qpA);
    const bf16x8 qA1 = *(const bf16x8*)(qpA + 32);
    const bf16x8 qB0 = *(const bf16x8*)(qpA + 16 * 64);
    const bf16x8 qB1 = *(const bf16x8*)(qpA + 16 * 64 + 32);

    // Staging: contents independent of wave->work mapping.
    const int sw = wave & 3;
    const int skey0 = (wave < 4) ? 0 : 1024;
    const size_t ksrc0 = (size_t)(skey0 + sw * 8 + (lane >> 3)) * 64
                       + 8 * ((lane & 7) ^ (lane >> 3));
    const size_t vsrc0 = (size_t)(sw * 16 + (lane >> 2)) * 2048 + skey0 + (lane & 3) * 8;

#define STAGE_ATTN(buf, itv) do {                                   \
    const size_t koff_ = ksrc0 + (size_t)(itv) * 32 * 64;           \
    gload_lds16(k1t + koff_, (buf) + wave * 512);                   \
    gload_lds16(k2t + koff_, (buf) + 4096 + wave * 512);            \
    gload_lds16(vtt + vsrc0 + (itv) * 32, (buf) + 8192 + wave * 512); \
} while (0)

    const int koffa = 8 * (quad ^ (l15 & 7));
    const int koffb = 8 * ((quad + 4) ^ (l15 & 7));
    const int vsw = 8 * (quad ^ ((l15 >> 1) & 3));   // matches proj's xh perm

    f32x4 OA[4], OB[4];
    float lA = 0.f, lB = 0.f;
#pragma unroll
    for (int t = 0; t < 4; ++t) {
        OA[t] = (f32x4){0.f, 0.f, 0.f, 0.f};
        OB[t] = (f32x4){0.f, 0.f, 0.f, 0.f};
    }

    STAGE_ATTN(smem[0], 0);
    __syncthreads();

    for (int it = 0; it < 32; ++it) {
        const bf16* sb = smem[it & 1];
        if (it < 31) STAGE_ATTN(smem[(it & 1) ^ 1], it + 1);

        // This wave reads ONLY its stream's K (4 reads) + V (4 reads).
        const bf16* kr = sb + st * 4096 + kg * 2048;
        const bf16* vr = sb + 8192 + kg * 2048;

        const bf16x8 kt0a = *(const bf16x8*)(kr + l15 * 64 + koffa);
        const bf16x8 kt0b = *(const bf16x8*)(kr + l15 * 64 + koffb);
        const bf16x8 kt1a = *(const bf16x8*)(kr + (16 + l15) * 64 + koffa);
        const bf16x8 kt1b = *(const bf16x8*)(kr + (16 + l15) * 64 + koffb);
        const bf16x8 v0 = *(const bf16x8*)(vr + l15 * 32 + vsw);
        const bf16x8 v1 = *(const bf16x8*)(vr + (16 + l15) * 32 + vsw);
        const bf16x8 v2 = *(const bf16x8*)(vr + (32 + l15) * 32 + vsw);
        const bf16x8 v3 = *(const bf16x8*)(vr + (48 + l15) * 32 + vsw);

        const f32x4 z = (f32x4){0.f, 0.f, 0.f, 0.f};
        __builtin_amdgcn_s_setprio(1);
        f32x4 sA0 = MFMA16(kt0a, qA0, z);  sA0 = MFMA16(kt0b, qA1, sA0);
        f32x4 sA1 = MFMA16(kt1a, qA0, z);  sA1 = MFMA16(kt1b, qA1, sA1);
        f32x4 sB0 = MFMA16(kt0a, qB0, z);  sB0 = MFMA16(kt0b, qB1, sB0);
        f32x4 sB1 = MFMA16(kt1a, qB0, z);  sB1 = MFMA16(kt1b, qB1, sB1);
        __builtin_amdgcn_s_setprio(0);

        bf16x8 bA, bB;
#pragma unroll
        for (int r = 0; r < 4; ++r) {
            float e;
            e = __builtin_amdgcn_exp2f(sA0[r]); lA += e; bA[r]     = (bf16)e;
            e = __builtin_amdgcn_exp2f(sA1[r]); lA += e; bA[4 + r] = (bf16)e;
            e = __builtin_amdgcn_exp2f(sB0[r]); lB += e; bB[r]     = (bf16)e;
            e = __builtin_amdgcn_exp2f(sB1[r]); lB += e; bB[4 + r] = (bf16)e;
        }

        __builtin_amdgcn_s_setprio(1);
        OA[0] = MFMA16(v0, bA, OA[0]);
        OA[1] = MFMA16(v1, bA, OA[1]);
        OA[2] = MFMA16(v2, bA, OA[2]);
        OA[3] = MFMA16(v3, bA, OA[3]);
        OB[0] = MFMA16(v0, bB, OB[0]);
        OB[1] = MFMA16(v1, bB, OB[1]);
        OB[2] = MFMA16(v2, bB, OB[2]);
        OB[3] = MFMA16(v3, bB, OB[3]);
        __builtin_amdgcn_s_setprio(0);

        __syncthreads();
    }

    // Quad-replica reduce of l, publish per-wave partial l.
    lA += __shfl_xor(lA, 16, 64);  lA += __shfl_xor(lA, 32, 64);
    lB += __shfl_xor(lB, 16, 64);  lB += __shfl_xor(lB, 32, 64);
    if (lane < 16) {
        lbuf[wave][0][lane] = lA;
        lbuf[wave][1][lane] = lB;
    }
    __syncthreads();

    // Stage 1: kg-combine. kg=1 waves export OA,OB; kg=0 waves accumulate.
    f32x4* rb = (f32x4*)smem;                     // 3072 f32x4 available
    if (kg == 1) {
        f32x4* dst = rb + w4 * 512;
#pragma unroll
        for (int t = 0; t < 4; ++t) {
            dst[t * 64 + lane]       = OA[t];
            dst[(4 + t) * 64 + lane] = OB[t];
        }
    }
    __syncthreads();
    if (kg == 0) {
        const f32x4* src = rb + w4 * 512;
#pragma unroll
        for (int t = 0; t < 4; ++t) {
            OA[t] += src[t * 64 + lane];
            OB[t] += src[(4 + t) * 64 + lane];
        }
    }
    __syncthreads();

    // Stage 2: stream-combine. kg=0,st=1 waves (2,3) export full-key O2.
    if (kg == 0 && st == 1) {
        f32x4* dst = rb + qp * 512;
#pragma unroll
        for (int t = 0; t < 4; ++t) {
            dst[t * 64 + lane]       = OA[t];
            dst[(4 + t) * 64 + lane] = OB[t];
        }
    }
    __syncthreads();

    float ssum = 0.f, ssq = 0.f;
    if (kg == 0 && st == 0) {                     // waves 0,1: final combine
        const f32x4* src = rb + qp * 512;         // stream-2 full-key O
        const float L1A = lA + lbuf[4 + qp][0][l15];
        const float L1B = lB + lbuf[4 + qp][1][l15];
        const float L2A = lbuf[2 + qp][0][l15] + lbuf[6 + qp][0][l15];
        const float L2B = lbuf[2 + qp][1][l15] + lbuf[6 + qp][1][l15];
        const float lam = __expf(lq1[h] * lk1[h]) - __expf(lq2[h] * lk2[h]) + LAMBDA_INIT;
        const float i1A = 1.f / L1A, i2A = lam / L2A;
        const float i1B = 1.f / L1B, i2B = lam / L2B;
        const size_t rowA = (size_t)(b * 2048 + qt * 64 + qp * 32 + l15) * 512 + h * 64;
        const size_t rowB = rowA + 16 * 512;
#pragma unroll
        for (int t = 0; t < 4; ++t) {
            const f32x4 o2A = src[t * 64 + lane];
            const f32x4 o2B = src[(4 + t) * 64 + lane];
#pragma unroll
            for (int r = 0; r < 4; ++r) {
                const float vA = OA[t][r] * i1A - o2A[r] * i2A;
                const float vB = OB[t][r] * i1B - o2B[r] * i2B;
                ssum += vA + vB;
                ssq += vA * vA + vB * vB;
                o[rowA + t * 16 + quad * 4 + r] = (bf16)vA;
                o[rowB + t * 16 + quad * 4 + r] = (bf16)vB;
            }
        }
    }
#pragma unroll
    for (int off = 1; off < 64; off <<= 1) {
        ssum += __shfl_xor(ssum, off, 64);
        ssq += __shfl_xor(ssq, off, 64);
    }
    if (kg == 0 && st == 0 && lane == 0) { sred[qp][0] = ssum; sred[qp][1] = ssq; }
    __syncthreads();
    if (tid == 0) {
        const float s0 = sred[0][0] + sred[1][0];
        const float s1 = sred[0][1] + sred[1][1];
        const int bg = b * 4 + (h >> 1);
        atomicAdd(&stats[bg * 2], s0);
        atomicAdd(&stats[bg * 2 + 1], s1);
    }
#undef STAGE_ATTN
}

// ---------------------------------------------------------------------------
// Kernel 4: output GEMM with GN folded algebraically. [r10 best]
// ---------------------------------------------------------------------------
__global__ __launch_bounds__(256) void out_gemm_kernel(
    const bf16* __restrict__ o, const bf16* __restrict__ owg,
    const float* __restrict__ S0, const float* __restrict__ stats,
    const float* __restrict__ ob, float* __restrict__ y)
{
    __shared__ __align__(16) bf16 sh[24576];   // 48 KB: 3x(A|B); reused as Tf

    const int tid = threadIdx.x;
    const int wave = tid >> 6, lane = tid & 63;
    const int l15 = lane & 15, quad = lane >> 4;

    // XCD swizzle: 512 blocks = 8 XCDs x 64.
    const int swzb = (blockIdx.x & 7) * 64 + (blockIdx.x >> 3);
    const int mb = swzb >> 3;
    const int nb = swzb & 7;
    const int b = mb >> 5;

    const float N = 128.f * 2048.f;
    float mu[4], rs[4];
#pragma unroll
    for (int g = 0; g < 4; ++g) {
        const float m = stats[(b * 4 + g) * 2] / N;
        const float var = stats[(b * 4 + g) * 2 + 1] / N - m * m;
        mu[g] = m;
        rs[g] = rsqrtf(var + EPS);
    }

    const int srow = lane >> 3;                   // 0..7
    const int scol = 8 * ((lane & 7) ^ srow);     // swizzled source col
    const bf16* ag = o + (size_t)(mb * 64 + srow) * 512 + scol;
    const bf16* bg = owg + (size_t)(nb * 64 + srow) * 512 + scol;

#define STAGE_OUT(abuf, bbuf, s) do {                                          \
    const int k0_ = (s) * 64;                                                  \
    _Pragma("unroll")                                                          \
    for (int c_ = 0; c_ < 2; ++c_) {                                           \
        const int chunk_ = wave * 2 + c_;                                      \
        gload_lds16(ag + (size_t)(chunk_ * 8) * 512 + k0_, (abuf) + chunk_ * 512); \
        gload_lds16(bg + (size_t)(chunk_ * 8) * 512 + k0_, (bbuf) + chunk_ * 512); \
    }                                                                          \
} while (0)

    f32x4 acc[4], tot[4];
#pragma unroll
    for (int i = 0; i < 4; ++i) {
        acc[i] = (f32x4){0.f, 0.f, 0.f, 0.f};
        tot[i] = (f32x4){0.f, 0.f, 0.f, 0.f};
    }
    float s1g[4];
    float s1p = 0.f;
#pragma unroll
    for (int g = 0; g < 4; ++g) s1g[g] = 0.f;

    // Prologue: stage kk=0 and kk=1 (8 loads in flight per wave).
    STAGE_OUT(sh, sh + 12288, 0);
    STAGE_OUT(sh + 4096, sh + 12288 + 4096, 1);

    const int ka = 8 * (quad ^ (l15 & 7));

    int cur = 0;
    for (int kk = 0; kk < 8; ++kk) {
        if (kk < 7) {
            asm volatile("s_waitcnt vmcnt(4) lgkmcnt(0)\ns_barrier" ::: "memory");
        } else {
            asm volatile("s_waitcnt vmcnt(0) lgkmcnt(0)\ns_barrier" ::: "memory");
        }
        __builtin_amdgcn_sched_barrier(0);

        const bf16* Ac = sh + cur * 4096;
        const bf16* Bc = sh + 12288 + cur * 4096;
        const int n2 = (cur == 0) ? 2 : cur - 1;      // (cur+2)%3
        if (kk < 6) STAGE_OUT(sh + n2 * 4096, sh + 12288 + n2 * 4096, kk + 2);

        bf16x8 al[4], ah[4];
#pragma unroll
        for (int i = 0; i < 4; ++i) {
            const bf16* p = Ac + (i * 16 + l15) * 64;
            al[i] = *(const bf16x8*)(p + ka);
            ah[i] = *(const bf16x8*)(p + (ka ^ 32));
        }
        const bf16* pb = Bc + (wave * 16 + l15) * 64;
        const bf16x8 bl = *(const bf16x8*)(pb + ka);
        const bf16x8 bh = *(const bf16x8*)(pb + (ka ^ 32));

#pragma unroll
        for (int i = 0; i < 4; ++i) {
            acc[i] = MFMA16(al[i], bl, acc[i]);
            acc[i] = MFMA16(ah[i], bh, acc[i]);
        }

#pragma unroll
        for (int j = 0; j < 8; ++j) s1p += (float)bl[j] + (float)bh[j];

        if (kk & 1) {
            const int g = kk >> 1;
#pragma unroll
            for (int i = 0; i < 4; ++i) {
#pragma unroll
                for (int r = 0; r < 4; ++r) tot[i][r] += rs[g] * acc[i][r];
                acc[i] = (f32x4){0.f, 0.f, 0.f, 0.f};
            }
            float sg = s1p + __shfl_xor(s1p, 16, 64);
            sg += __shfl_xor(sg, 32, 64);
            s1g[g] = sg;
            s1p = 0.f;
        }

        cur = (cur == 2) ? 0 : cur + 1;
    }
    __syncthreads();      // all waves past the loop; sh reusable as Tf

    const int ncol = nb * 64 + wave * 16 + l15;
    float bias = S0[ncol] + ob[ncol];
#pragma unroll
    for (int g = 0; g < 4; ++g) bias -= mu[g] * rs[g] * s1g[g];

    // LDS-staged epilogue: Tf[m][n ^ (quad(m)<<4)] f32, then coalesced rows.
    float* const Tf = (float*)sh;                 // 64x64 f32 = 16 KB
    const int nl = wave * 16 + l15;
#pragma unroll
    for (int i = 0; i < 4; ++i) {
        const int mbase = i * 16 + quad * 4;
#pragma unroll
        for (int r = 0; r < 4; ++r)
            Tf[(mbase + r) * 64 + (nl ^ (quad << 4))] = tot[i][r] + bias;
    }
    __syncthreads();

#pragma unroll
    for (int ps = 0; ps < 4; ++ps) {
        const int idx = (ps * 256 + tid) * 4;     // 0..4095
        const int m = idx >> 6, n4 = idx & 63;
        const f32x4 v = *(const f32x4*)(Tf + m * 64 + (n4 ^ (((m >> 2) & 3) << 4)));
        *(f32x4*)(y + (size_t)(mb * 64 + m) * 512 + nb * 64 + n4) = v;
    }
#undef STAGE_OUT
}

// ---------------------------------------------------------------------------
extern "C" void kernel_launch(void* const* d_in, const int* in_sizes, int n_in,
                              void* d_out, int out_size, void* d_ws, size_t ws_size,
                              hipStream_t stream)
{
    const float* x   = (const float*)d_in[0];
    const float* K1w = (const float*)d_in[1];
    const float* K1b = (const float*)d_in[2];
    const float* Q1w = (const float*)d_in[3];
    const float* K2w = (const float*)d_in[4];
    const float* K2b = (const float*)d_in[5];
    const float* Q2w = (const float*)d_in[6];
    const float* Vw  = (const float*)d_in[7];
    const float* lq1 = (const float*)d_in[8];
    const float* lk1 = (const float*)d_in[9];
    const float* lq2 = (const float*)d_in[10];
    const float* lk2 = (const float*)d_in[11];
    const float* gnw = (const float*)d_in[12];
    const float* gnb = (const float*)d_in[13];
    const float* Ow  = (const float*)d_in[14];
    const float* Ob  = (const float*)d_in[15];

    const size_t SZ = (size_t)2 * 8 * 2048 * 64;   // 2M elements per tensor
    bf16* q1 = (bf16*)d_ws;
    bf16* k1 = q1 + SZ;
    bf16* q2 = k1 + SZ;
    bf16* k2 = q2 + SZ;
    bf16* vt = k2 + SZ;
    bf16* o  = vt + SZ;                 // attn output; slot shared with xb
    bf16* xb = o;                       // x bf16 (2M elems) — dead before attn writes o
    bf16* wb = o + SZ;                  // 2560x512 bf16 (2.6 MB)
    bf16* owg = wb + (size_t)2560 * 512;
    float* S0 = (float*)(owg + 512 * 512);
    float* stats = S0 + 512;

    prep_kernel<<<1696, 256, 0, stream>>>(x, Q1w, K1w, Q2w, K2w, Vw,
                                          Ow, gnw, gnb, xb, wb, owg, S0, stats);
    proj_kernel<<<640, 256, 0, stream>>>(xb, wb, K1b, K2b,
                                         q1, k1, q2, k2, vt);
    attn_kernel<<<512, 512, 0, stream>>>(q1, k1, q2, k2, vt,
                                         lq1, lk1, lq2, lk2, o, stats);
    out_gemm_kernel<<<512, 256, 0, stream>>>(o, owg, S0, stats, Ob,
                                             (float*)d_out);
}